// Round 1
// baseline (756.470 us; speedup 1.0000x reference)
//
#include <hip/hip_runtime.h>

#define NSEQ 512
#define DCH 128
#define RTOT (NSEQ * NSEQ) /* 262144 */

typedef __attribute__((ext_vector_type(8))) short bf16x8;
typedef __attribute__((ext_vector_type(4))) float f32x4;

__device__ __forceinline__ unsigned short f2bf(float v) {
  union { float f; unsigned int u; } x; x.f = v;
  unsigned int u = x.u;
  return (unsigned short)((u + 0x7fffu + ((u >> 16) & 1u)) >> 16);
}
__device__ __forceinline__ float bf2f(unsigned short s) {
  union { unsigned int u; float f; } x; x.u = ((unsigned int)s) << 16;
  return x.f;
}
__device__ __forceinline__ float sigmoidf(float x) { return 1.f / (1.f + __expf(-x)); }

// async global->LDS, 16B per lane; LDS dst is wave-uniform base (+ lane*16 implicit)
__device__ __forceinline__ void async16(const unsigned short* g, unsigned short* l) {
  __builtin_amdgcn_global_load_lds(
      (const __attribute__((address_space(1))) unsigned int*)g,
      (__attribute__((address_space(3))) unsigned int*)l, 16, 0, 0);
}

// ---------------------------------------------------------------------------
// prep: pack weights (reordered) into bf16.  Wc rows: [0,128)=to-feat,
// [128,256)=to-gate, [256,384)=from-feat, [384,512)=from-gate, [512,640)=go.
// ---------------------------------------------------------------------------
__global__ void prep_kernel(const float* __restrict__ W_fg, const float* __restrict__ b_fg,
                            const float* __restrict__ W_go, const float* __restrict__ b_go,
                            const float* __restrict__ W_out,
                            unsigned short* __restrict__ Wc, float* __restrict__ bc,
                            unsigned short* __restrict__ Woutb) {
  int idx = blockIdx.x * 256 + threadIdx.x;
  if (idx < 640 * 128) {
    int rr = idx >> 7, k = idx & 127;
    float v, bv;
    if (rr < 512) {
      int m = rr >> 7;
      int srow = (m == 1) ? rr + 128 : (m == 2) ? rr - 128 : rr;
      v = W_fg[srow * 128 + k];
      bv = b_fg[srow];
    } else {
      int srow = rr - 512;
      v = W_go[srow * 128 + k];
      bv = b_go[srow];
    }
    Wc[idx] = f2bf(v);
    if (k == 0) bc[rr] = bv;
  } else {
    int i2 = idx - 640 * 128;
    if (i2 < 128 * 128) Woutb[i2] = f2bf(W_out[i2]);
  }
}

// ---------------------------------------------------------------------------
// K0: LayerNorm over last dim (128) of edges; write x as bf16. 1 wave = 1 row.
// ---------------------------------------------------------------------------
__global__ __launch_bounds__(256) void ln1_kernel(const float* __restrict__ edges,
                                                  const float* __restrict__ w,
                                                  const float* __restrict__ b,
                                                  unsigned short* __restrict__ xb) {
  int wv = threadIdx.x >> 6;
  int lane = threadIdx.x & 63;
  size_t row = (size_t)blockIdx.x * 4 + wv;
  const float2* e = (const float2*)(edges + row * 128);
  float2 v = e[lane];
  float s = v.x + v.y, sq = v.x * v.x + v.y * v.y;
#pragma unroll
  for (int off = 32; off; off >>= 1) {
    s += __shfl_xor(s, off);
    sq += __shfl_xor(sq, off);
  }
  float mu = s * (1.f / 128.f);
  float var = sq * (1.f / 128.f) - mu * mu;
  float rs = rsqrtf(var + 1e-5f);
  int c = lane * 2;
  float x0 = (v.x - mu) * rs * w[c] + b[c];
  float x1 = (v.y - mu) * rs * w[c + 1] + b[c + 1];
  unsigned int packed = (unsigned int)f2bf(x0) | ((unsigned int)f2bf(x1) << 16);
  ((unsigned int*)(xb + row * 128))[lane] = packed;
}

// ---------------------------------------------------------------------------
// K1a: fg GEMM + gating + mask. Block: 64 rows x 256 cols (128 gated out), K=128.
// blockIdx.y: 0 -> to, 1 -> from. Epilogue transposes through LDS so channel-
// major stores are full 128B lines (8 lanes/plane x uint4) instead of 32B chunks.
// ---------------------------------------------------------------------------
__global__ __launch_bounds__(256) void fg_gemm_kernel(
    const unsigned short* __restrict__ xb, const unsigned short* __restrict__ Wc,
    const float* __restrict__ bc, const int* __restrict__ mask,
    unsigned short* __restrict__ toT, unsigned short* __restrict__ fromT) {
  __shared__ unsigned int Cs[128 * 36]; // 128 planes x 64 rows bf16, pad 36 uints/plane (18KB)
  int nb = blockIdx.y;
  int wv = threadIdx.x >> 6, lane = threadIdx.x & 63;
  int qm = lane & 15, quad = lane >> 4;
  int rw = blockIdx.x * 64 + wv * 16;
  int nbase = nb * 256;

  f32x4 acc[16];
#pragma unroll
  for (int t = 0; t < 16; t++) acc[t] = (f32x4){0.f, 0.f, 0.f, 0.f};

#pragma unroll
  for (int kk = 0; kk < 4; kk++) {
    int ko = kk * 32 + quad * 8;
    bf16x8 a = *(const bf16x8*)(xb + (size_t)(rw + qm) * 128 + ko);
#pragma unroll
    for (int t = 0; t < 16; t++) {
      bf16x8 bf = *(const bf16x8*)(Wc + (size_t)(nbase + t * 16 + qm) * 128 + ko);
      acc[t] = __builtin_amdgcn_mfma_f32_16x16x32_bf16(a, bf, acc[t], 0, 0, 0);
    }
  }

  int rbase = rw + quad * 4;
  int4 mi = *(const int4*)(mask + rbase);
  float mk[4] = {mi.x ? 1.f : 0.f, mi.y ? 1.f : 0.f, mi.z ? 1.f : 0.f, mi.w ? 1.f : 0.f};
#pragma unroll
  for (int t = 0; t < 8; t++) {
    int c = t * 16 + qm;
    float bF = bc[nbase + c];
    float bG = bc[nbase + 128 + c];
    float v0 = (acc[t][0] + bF) * sigmoidf(acc[t + 8][0] + bG) * mk[0];
    float v1 = (acc[t][1] + bF) * sigmoidf(acc[t + 8][1] + bG) * mk[1];
    float v2 = (acc[t][2] + bF) * sigmoidf(acc[t + 8][2] + bG) * mk[2];
    float v3 = (acc[t][3] + bF) * sigmoidf(acc[t + 8][3] + bG) * mk[3];
    unsigned int u0 = (unsigned int)f2bf(v0) | ((unsigned int)f2bf(v1) << 16);
    unsigned int u1 = (unsigned int)f2bf(v2) | ((unsigned int)f2bf(v3) << 16);
    // plane c, local rows wv*16+quad*4 .. +3  (uint index = row/2)
    *(uint2*)(Cs + c * 36 + wv * 8 + quad * 2) = (uint2){u0, u1};
  }
  __syncthreads();
  { // each wave writes 32 planes; 8 lanes per plane -> 128B contiguous lines
    unsigned short* dst = (nb == 0) ? toT : fromT;
    int rb0 = blockIdx.x * 64;
    int pl = lane >> 3, lo = lane & 7;
#pragma unroll
    for (int i = 0; i < 4; i++) {
      int p = wv * 32 + i * 8 + pl;
      uint4 v = *(const uint4*)(Cs + p * 36 + lo * 4);
      *(uint4*)(dst + (size_t)p * RTOT + rb0 + lo * 8) = v;
    }
  }
}

// ---------------------------------------------------------------------------
// K1b (FALLBACK ONLY, used when workspace too small to de-alias triT):
// out_gate = sigmoid(x @ W_go^T + b_go) * mask, fp32, into d_out.
// ---------------------------------------------------------------------------
__global__ __launch_bounds__(256) void go_gemm_kernel(
    const unsigned short* __restrict__ xb, const unsigned short* __restrict__ Wc,
    const float* __restrict__ bc, const int* __restrict__ mask,
    float* __restrict__ gate_out) {
  int wv = threadIdx.x >> 6, lane = threadIdx.x & 63;
  int qm = lane & 15, quad = lane >> 4;
  int rw = blockIdx.x * 64 + wv * 16;

  f32x4 acc[8];
#pragma unroll
  for (int t = 0; t < 8; t++) acc[t] = (f32x4){0.f, 0.f, 0.f, 0.f};

#pragma unroll
  for (int kk = 0; kk < 4; kk++) {
    int ko = kk * 32 + quad * 8;
    bf16x8 a = *(const bf16x8*)(xb + (size_t)(rw + qm) * 128 + ko);
#pragma unroll
    for (int t = 0; t < 8; t++) {
      bf16x8 bf = *(const bf16x8*)(Wc + (size_t)(512 + t * 16 + qm) * 128 + ko);
      acc[t] = __builtin_amdgcn_mfma_f32_16x16x32_bf16(a, bf, acc[t], 0, 0, 0);
    }
  }

  int rbase = rw + quad * 4;
  int4 mi = *(const int4*)(mask + rbase);
  float mk[4] = {mi.x ? 1.f : 0.f, mi.y ? 1.f : 0.f, mi.z ? 1.f : 0.f, mi.w ? 1.f : 0.f};
#pragma unroll
  for (int t = 0; t < 8; t++) {
    int c = t * 16 + qm;
    float bG = bc[512 + c];
#pragma unroll
    for (int reg = 0; reg < 4; reg++) {
      float g = sigmoidf(acc[t][reg] + bG) * mk[reg];
      gate_out[(size_t)(rbase + reg) * 128 + c] = g;
    }
  }
}

// ---------------------------------------------------------------------------
// K2: tri[d] = To_d (512x512) @ From_d^T, 128 batched NT GEMMs.
// 128x128 tile/block, BK=64, global_load_lds(16B) staging, 4 waves x (4x4)
// MFMA accs. Epilogue repacks C through padded LDS -> dwordx4 stores.
// ---------------------------------------------------------------------------
__global__ __launch_bounds__(256) void tri_gemm_kernel(
    const unsigned short* __restrict__ toT, const unsigned short* __restrict__ fromT,
    unsigned short* __restrict__ triT) {
  __shared__ unsigned short smem[128 * 136]; // K-loop: As=[0,8192) Bs=[8192,16384); epilogue: C 128x136
  unsigned short* As = smem;
  unsigned short* Bs = smem + 128 * 64;

  int d = blockIdx.z;
  int i0 = blockIdx.x * 128, j0 = blockIdx.y * 128;
  int tid = threadIdx.x, w = tid >> 6, lane = tid & 63;
  int qm = lane & 15, quad = lane >> 4;
  int wm = w >> 1, wn = w & 1;
  const unsigned short* A = toT + (size_t)d * RTOT;
  const unsigned short* B = fromT + (size_t)d * RTOT;
  int lr = lane >> 3, lk = (lane & 7) * 8;

  f32x4 acc[4][4];
#pragma unroll
  for (int m = 0; m < 4; m++)
#pragma unroll
    for (int n = 0; n < 4; n++) acc[m][n] = (f32x4){0.f, 0.f, 0.f, 0.f};

  for (int kb = 0; kb < 512; kb += 64) {
    __syncthreads(); // prev compute done reading LDS
#pragma unroll
    for (int q = 0; q < 4; q++) {
      int blk = w * 4 + q; // 16 row-blocks of 8 rows each
      async16(A + (size_t)(i0 + blk * 8 + lr) * 512 + kb + lk, As + blk * 512);
      async16(B + (size_t)(j0 + blk * 8 + lr) * 512 + kb + lk, Bs + blk * 512);
    }
    __syncthreads(); // loads drained (compiler emits vmcnt(0) before barrier)
#pragma unroll
    for (int kk = 0; kk < 2; kk++) {
      bf16x8 af[4], bfr[4];
#pragma unroll
      for (int m = 0; m < 4; m++)
        af[m] = *(const bf16x8*)(As + (wm * 64 + m * 16 + qm) * 64 + kk * 32 + quad * 8);
#pragma unroll
      for (int n = 0; n < 4; n++)
        bfr[n] = *(const bf16x8*)(Bs + (wn * 64 + n * 16 + qm) * 64 + kk * 32 + quad * 8);
#pragma unroll
      for (int m = 0; m < 4; m++)
#pragma unroll
        for (int n = 0; n < 4; n++)
          acc[m][n] = __builtin_amdgcn_mfma_f32_16x16x32_bf16(af[m], bfr[n], acc[m][n], 0, 0, 0);
    }
  }

  __syncthreads(); // done with As/Bs; reuse smem as C 128x136 (pad keeps 16B align, kills conflicts)
#pragma unroll
  for (int m = 0; m < 4; m++) {
    int rb = wm * 64 + m * 16 + quad * 4;
#pragma unroll
    for (int n = 0; n < 4; n++) {
      int col = wn * 64 + n * 16 + qm;
#pragma unroll
      for (int reg = 0; reg < 4; reg++)
        smem[(rb + reg) * 136 + col] = f2bf(acc[m][n][reg]);
    }
  }
  __syncthreads();
  { // each (row, half) copies its FULL 64-short half: 8 x uint4
    int row = tid >> 1, half = tid & 1;
    const uint4* src = (const uint4*)(smem + row * 136 + half * 64);
    uint4 v[8];
#pragma unroll
    for (int u = 0; u < 8; u++) v[u] = src[u];
    uint4* dst = (uint4*)(triT + (size_t)d * RTOT + (size_t)(i0 + row) * 512 + j0 + half * 64);
#pragma unroll
    for (int u = 0; u < 8; u++) dst[u] = v[u];
  }
}

// ---------------------------------------------------------------------------
// K3: LN2 over d=128 of tri (channel-major input), @ W_out^T + b_out, * gate.
// fuse==1: recompute gate in-register from xb (go GEMM fused; d_out write-only).
// fuse==0: legacy path, gate pre-stored fp32 in d_out (RMW).
// ---------------------------------------------------------------------------
__global__ __launch_bounds__(256) void out_kernel(
    const unsigned short* __restrict__ triT, const unsigned short* __restrict__ Woutb,
    const float* __restrict__ ln2w, const float* __restrict__ ln2b,
    const float* __restrict__ b_out, float* __restrict__ out,
    const unsigned short* __restrict__ xb, const unsigned short* __restrict__ Wc,
    const float* __restrict__ bc, const int* __restrict__ mask, int fuse) {
  __shared__ unsigned short nt[64][136];
  __shared__ float mu_s[64], rs_s[64];
  int r0 = blockIdx.x * 64;
  int tid = threadIdx.x;

  { // stage 64 rows x 128 ch, transposing channel-major -> row-major
    int dch = tid >> 1, half = tid & 1;
    const uint4* src = (const uint4*)(triT + (size_t)dch * RTOT + r0 + half * 32);
    uint4 v[4];
    v[0] = src[0]; v[1] = src[1]; v[2] = src[2]; v[3] = src[3];
    const unsigned short* pv = (const unsigned short*)v;
#pragma unroll
    for (int u = 0; u < 32; u++) nt[half * 32 + u][dch] = pv[u];
  }
  __syncthreads();

  { // LN2 stats: 4 lanes per position
    int p = tid >> 2, part = tid & 3;
    float s = 0.f, sq = 0.f;
#pragma unroll
    for (int u = 0; u < 4; u++) {
      bf16x8 v = *(const bf16x8*)(&nt[p][part * 32 + u * 8]);
#pragma unroll
      for (int e = 0; e < 8; e++) {
        float f = bf2f((unsigned short)v[e]);
        s += f; sq += f * f;
      }
    }
    s += __shfl_xor(s, 1); sq += __shfl_xor(sq, 1);
    s += __shfl_xor(s, 2); sq += __shfl_xor(sq, 2);
    float mu = s * (1.f / 128.f);
    float var = sq * (1.f / 128.f) - mu * mu;
    if (part == 0) { mu_s[p] = mu; rs_s[p] = rsqrtf(var + 1e-5f); }
  }
  __syncthreads();

  int wv = tid >> 6, lane = tid & 63;
  int qm = lane & 15, quad = lane >> 4;
  int p = wv * 16 + qm;
  float mu = mu_s[p], rs = rs_s[p];

  bf16x8 afr[4];
#pragma unroll
  for (int kk = 0; kk < 4; kk++) { // build normalized A-fragments
    int ko = kk * 32 + quad * 8;
    bf16x8 raw = *(const bf16x8*)(&nt[p][ko]);
#pragma unroll
    for (int e = 0; e < 8; e++) {
      float wf = ln2w[ko + e], bv = ln2b[ko + e];
      afr[kk][e] = (short)f2bf((bf2f((unsigned short)raw[e]) - mu) * rs * wf + bv);
    }
  }

  f32x4 acc[8];
#pragma unroll
  for (int t = 0; t < 8; t++) acc[t] = (f32x4){0.f, 0.f, 0.f, 0.f};
#pragma unroll
  for (int kk = 0; kk < 4; kk++) {
    int ko = kk * 32 + quad * 8;
#pragma unroll
    for (int t = 0; t < 8; t++) {
      bf16x8 bf = *(const bf16x8*)(Woutb + (size_t)(t * 16 + qm) * 128 + ko);
      acc[t] = __builtin_amdgcn_mfma_f32_16x16x32_bf16(afr[kk], bf, acc[t], 0, 0, 0);
    }
  }

  int rbase = r0 + wv * 16 + quad * 4;
  if (fuse) {
    // fused out_gate: acc2 = xb @ W_go^T (same fragment geometry as go_gemm)
    f32x4 acc2[8];
#pragma unroll
    for (int t = 0; t < 8; t++) acc2[t] = (f32x4){0.f, 0.f, 0.f, 0.f};
    const unsigned short* xrow = xb + (size_t)(r0 + wv * 16 + qm) * 128;
#pragma unroll
    for (int kk = 0; kk < 4; kk++) {
      int ko = kk * 32 + quad * 8;
      bf16x8 a2 = *(const bf16x8*)(xrow + ko);
#pragma unroll
      for (int t = 0; t < 8; t++) {
        bf16x8 bf = *(const bf16x8*)(Wc + (size_t)(512 + t * 16 + qm) * 128 + ko);
        acc2[t] = __builtin_amdgcn_mfma_f32_16x16x32_bf16(a2, bf, acc2[t], 0, 0, 0);
      }
    }
    int4 mi = *(const int4*)(mask + rbase);
    float mk[4] = {mi.x ? 1.f : 0.f, mi.y ? 1.f : 0.f, mi.z ? 1.f : 0.f, mi.w ? 1.f : 0.f};
#pragma unroll
    for (int t = 0; t < 8; t++) {
      int c = t * 16 + qm;
      float bo = b_out[c];
      float bG = bc[512 + c];
#pragma unroll
      for (int reg = 0; reg < 4; reg++) {
        float g = sigmoidf(acc2[t][reg] + bG) * mk[reg];
        out[(size_t)(rbase + reg) * 128 + c] = (acc[t][reg] + bo) * g;
      }
    }
  } else {
#pragma unroll
    for (int t = 0; t < 8; t++) {
      int c = t * 16 + qm;
      float bo = b_out[c];
#pragma unroll
      for (int reg = 0; reg < 4; reg++) {
        size_t off = (size_t)(rbase + reg) * 128 + c;
        out[off] = (acc[t][reg] + bo) * out[off]; // out[] currently holds gate
      }
    }
  }
}

// ---------------------------------------------------------------------------
extern "C" void kernel_launch(void* const* d_in, const int* in_sizes, int n_in,
                              void* d_out, int out_size, void* d_ws, size_t ws_size,
                              hipStream_t stream) {
  const float* edges = (const float*)d_in[0];
  const int* mask = (const int*)d_in[1];
  const float* ln1w = (const float*)d_in[2];
  const float* ln1b = (const float*)d_in[3];
  const float* W_fg = (const float*)d_in[4];
  const float* b_fg = (const float*)d_in[5];
  const float* W_go = (const float*)d_in[6];
  const float* b_go = (const float*)d_in[7];
  const float* ln2w = (const float*)d_in[8];
  const float* ln2b = (const float*)d_in[9];
  const float* W_out = (const float*)d_in[10];
  const float* b_out = (const float*)d_in[11];

  char* ws = (char*)d_ws;
  const size_t SZ = (size_t)RTOT * DCH * 2; // 64 MiB per bf16 buffer
  const size_t WSMALL = 0x40000;            // 256 KiB: Wc(160K)+bc(2.5K)+Woutb(32K), padded
  unsigned short* xb = (unsigned short*)ws;
  unsigned short* toT = (unsigned short*)(ws + SZ);
  unsigned short* fromT = (unsigned short*)(ws + 2 * SZ);
  unsigned short* Wc = (unsigned short*)(ws + 3 * SZ);
  float* bc = (float*)(ws + 3 * SZ + 640 * 128 * 2);
  unsigned short* Woutb = (unsigned short*)(ws + 3 * SZ + 640 * 128 * 2 + 640 * 4);
  float* gate = (float*)d_out;

  // If workspace allows, give triT its own buffer so xb survives -> fuse the
  // gate GEMM into out_kernel (kills 256 MiB of fp32 gate traffic + 1 launch).
  bool fits = ws_size >= 4 * SZ + WSMALL;
  unsigned short* triT = fits ? (unsigned short*)(ws + 3 * SZ + WSMALL) : xb;

  prep_kernel<<<384, 256, 0, stream>>>(W_fg, b_fg, W_go, b_go, W_out, Wc, bc, Woutb);
  ln1_kernel<<<RTOT / 4, 256, 0, stream>>>(edges, ln1w, ln1b, xb);
  fg_gemm_kernel<<<dim3(RTOT / 64, 2), 256, 0, stream>>>(xb, Wc, bc, mask, toT, fromT);
  if (!fits) go_gemm_kernel<<<RTOT / 64, 256, 0, stream>>>(xb, Wc, bc, mask, gate);
  tri_gemm_kernel<<<dim3(4, 4, 128), 256, 0, stream>>>(toT, fromT, triT);
  out_kernel<<<RTOT / 64, 256, 0, stream>>>(triT, Woutb, ln2w, ln2b, b_out,
                                            (float*)d_out, xb, Wc, bc, mask, fits ? 1 : 0);
}

// Round 2
// 625.398 us; speedup vs baseline: 1.2096x; 1.2096x over previous
//
#include <hip/hip_runtime.h>

#define NSEQ 512
#define DCH 128
#define RTOT (NSEQ * NSEQ) /* 262144 */

typedef __attribute__((ext_vector_type(8))) short bf16x8;
typedef __attribute__((ext_vector_type(4))) float f32x4;

__device__ __forceinline__ unsigned short f2bf(float v) {
  union { float f; unsigned int u; } x; x.f = v;
  unsigned int u = x.u;
  return (unsigned short)((u + 0x7fffu + ((u >> 16) & 1u)) >> 16);
}
__device__ __forceinline__ float bf2f(unsigned short s) {
  union { unsigned int u; float f; } x; x.u = ((unsigned int)s) << 16;
  return x.f;
}
__device__ __forceinline__ float sigmoidf(float x) { return 1.f / (1.f + __expf(-x)); }

// async global->LDS, 16B per lane; LDS dst is wave-uniform base (+ lane*16 implicit)
__device__ __forceinline__ void async16(const unsigned short* g, unsigned short* l) {
  __builtin_amdgcn_global_load_lds(
      (const __attribute__((address_space(1))) unsigned int*)g,
      (__attribute__((address_space(3))) unsigned int*)l, 16, 0, 0);
}

// ---------------------------------------------------------------------------
// prep: pack weights (reordered) into bf16.  Wc rows: [0,128)=to-feat,
// [128,256)=to-gate, [256,384)=from-feat, [384,512)=from-gate, [512,640)=go.
// ---------------------------------------------------------------------------
__global__ void prep_kernel(const float* __restrict__ W_fg, const float* __restrict__ b_fg,
                            const float* __restrict__ W_go, const float* __restrict__ b_go,
                            const float* __restrict__ W_out,
                            unsigned short* __restrict__ Wc, float* __restrict__ bc,
                            unsigned short* __restrict__ Woutb) {
  int idx = blockIdx.x * 256 + threadIdx.x;
  if (idx < 640 * 128) {
    int rr = idx >> 7, k = idx & 127;
    float v, bv;
    if (rr < 512) {
      int m = rr >> 7;
      int srow = (m == 1) ? rr + 128 : (m == 2) ? rr - 128 : rr;
      v = W_fg[srow * 128 + k];
      bv = b_fg[srow];
    } else {
      int srow = rr - 512;
      v = W_go[srow * 128 + k];
      bv = b_go[srow];
    }
    Wc[idx] = f2bf(v);
    if (k == 0) bc[rr] = bv;
  } else {
    int i2 = idx - 640 * 128;
    if (i2 < 128 * 128) Woutb[i2] = f2bf(W_out[i2]);
  }
}

// ---------------------------------------------------------------------------
// K0: LayerNorm over last dim (128) of edges; write x as bf16. 1 wave = 1 row.
// ---------------------------------------------------------------------------
__global__ __launch_bounds__(256) void ln1_kernel(const float* __restrict__ edges,
                                                  const float* __restrict__ w,
                                                  const float* __restrict__ b,
                                                  unsigned short* __restrict__ xb) {
  int wv = threadIdx.x >> 6;
  int lane = threadIdx.x & 63;
  size_t row = (size_t)blockIdx.x * 4 + wv;
  const float2* e = (const float2*)(edges + row * 128);
  float2 v = e[lane];
  float s = v.x + v.y, sq = v.x * v.x + v.y * v.y;
#pragma unroll
  for (int off = 32; off; off >>= 1) {
    s += __shfl_xor(s, off);
    sq += __shfl_xor(sq, off);
  }
  float mu = s * (1.f / 128.f);
  float var = sq * (1.f / 128.f) - mu * mu;
  float rs = rsqrtf(var + 1e-5f);
  int c = lane * 2;
  float x0 = (v.x - mu) * rs * w[c] + b[c];
  float x1 = (v.y - mu) * rs * w[c + 1] + b[c + 1];
  unsigned int packed = (unsigned int)f2bf(x0) | ((unsigned int)f2bf(x1) << 16);
  ((unsigned int*)(xb + row * 128))[lane] = packed;
}

// ---------------------------------------------------------------------------
// K1a: fg GEMM + gating + mask.  Col-split waves: each wave owns 32 paired
// feat/gate cols x all 64 block rows; its 16 Wc B-fragments are hoisted into
// registers BEFORE the row loop (Wc is 160KB, block-invariant -> kills the
// per-MFMA L2 round-trips that made this kernel latency-bound: MfmaUtil was
// 4.9%).  Each wave writes+reads its own 32 Cs planes (one barrier for safety).
// ---------------------------------------------------------------------------
__global__ __launch_bounds__(256) void fg_gemm_kernel(
    const unsigned short* __restrict__ xb, const unsigned short* __restrict__ Wc,
    const float* __restrict__ bc, const int* __restrict__ mask,
    unsigned short* __restrict__ toT, unsigned short* __restrict__ fromT) {
  __shared__ unsigned int Cs[128 * 36]; // 128 planes x 64 rows bf16 (pad 36 uints/plane)
  int nb = blockIdx.y;
  int wv = threadIdx.x >> 6, lane = threadIdx.x & 63;
  int qm = lane & 15, quad = lane >> 4;
  int r0 = blockIdx.x * 64;
  int nbase = nb * 256;

  // Hoisted B fragments: feat cols nbase+wv*32+ft*16, gate cols +128.
  bf16x8 Bf[2][4], Bg[2][4];
#pragma unroll
  for (int ft = 0; ft < 2; ft++)
#pragma unroll
    for (int kk = 0; kk < 4; kk++) {
      int ko = kk * 32 + quad * 8;
      Bf[ft][kk] = *(const bf16x8*)(Wc + (size_t)(nbase + wv * 32 + ft * 16 + qm) * 128 + ko);
      Bg[ft][kk] = *(const bf16x8*)(Wc + (size_t)(nbase + 128 + wv * 32 + ft * 16 + qm) * 128 + ko);
    }

#pragma unroll
  for (int m = 0; m < 4; m++) { // 4 row-steps of 16 rows
    int rw = r0 + m * 16;
    f32x4 accf[2], accg[2];
#pragma unroll
    for (int ft = 0; ft < 2; ft++) {
      accf[ft] = (f32x4){0.f, 0.f, 0.f, 0.f};
      accg[ft] = (f32x4){0.f, 0.f, 0.f, 0.f};
    }
#pragma unroll
    for (int kk = 0; kk < 4; kk++) {
      int ko = kk * 32 + quad * 8;
      bf16x8 a = *(const bf16x8*)(xb + (size_t)(rw + qm) * 128 + ko);
#pragma unroll
      for (int ft = 0; ft < 2; ft++) {
        accf[ft] = __builtin_amdgcn_mfma_f32_16x16x32_bf16(a, Bf[ft][kk], accf[ft], 0, 0, 0);
        accg[ft] = __builtin_amdgcn_mfma_f32_16x16x32_bf16(a, Bg[ft][kk], accg[ft], 0, 0, 0);
      }
    }
    int rbase = rw + quad * 4;
    int4 mi = *(const int4*)(mask + rbase);
    float mk[4] = {mi.x ? 1.f : 0.f, mi.y ? 1.f : 0.f, mi.z ? 1.f : 0.f, mi.w ? 1.f : 0.f};
#pragma unroll
    for (int ft = 0; ft < 2; ft++) {
      int c = wv * 32 + ft * 16 + qm; // local col 0..127
      float bF = bc[nbase + c];
      float bG = bc[nbase + 128 + c];
      float v0 = (accf[ft][0] + bF) * sigmoidf(accg[ft][0] + bG) * mk[0];
      float v1 = (accf[ft][1] + bF) * sigmoidf(accg[ft][1] + bG) * mk[1];
      float v2 = (accf[ft][2] + bF) * sigmoidf(accg[ft][2] + bG) * mk[2];
      float v3 = (accf[ft][3] + bF) * sigmoidf(accg[ft][3] + bG) * mk[3];
      unsigned int u0 = (unsigned int)f2bf(v0) | ((unsigned int)f2bf(v1) << 16);
      unsigned int u1 = (unsigned int)f2bf(v2) | ((unsigned int)f2bf(v3) << 16);
      *(uint2*)(Cs + c * 36 + m * 8 + quad * 2) = (uint2){u0, u1};
    }
  }
  __syncthreads(); // cheap safety: wave's planes are its own, but guarantee LDS order
  { // wave writes its own 32 planes; 8 lanes/plane -> 128B contiguous lines
    unsigned short* dst = (nb == 0) ? toT : fromT;
    int pl = lane >> 3, lo = lane & 7;
#pragma unroll
    for (int i = 0; i < 4; i++) {
      int p = wv * 32 + i * 8 + pl;
      uint4 v = *(const uint4*)(Cs + p * 36 + lo * 4);
      *(uint4*)(dst + (size_t)p * RTOT + r0 + lo * 8) = v;
    }
  }
}

// ---------------------------------------------------------------------------
// K1b (FALLBACK ONLY, used when workspace too small to de-alias triT):
// out_gate = sigmoid(x @ W_go^T + b_go) * mask, fp32, into d_out.
// ---------------------------------------------------------------------------
__global__ __launch_bounds__(256) void go_gemm_kernel(
    const unsigned short* __restrict__ xb, const unsigned short* __restrict__ Wc,
    const float* __restrict__ bc, const int* __restrict__ mask,
    float* __restrict__ gate_out) {
  int wv = threadIdx.x >> 6, lane = threadIdx.x & 63;
  int qm = lane & 15, quad = lane >> 4;
  int rw = blockIdx.x * 64 + wv * 16;

  f32x4 acc[8];
#pragma unroll
  for (int t = 0; t < 8; t++) acc[t] = (f32x4){0.f, 0.f, 0.f, 0.f};

#pragma unroll
  for (int kk = 0; kk < 4; kk++) {
    int ko = kk * 32 + quad * 8;
    bf16x8 a = *(const bf16x8*)(xb + (size_t)(rw + qm) * 128 + ko);
#pragma unroll
    for (int t = 0; t < 8; t++) {
      bf16x8 bf = *(const bf16x8*)(Wc + (size_t)(512 + t * 16 + qm) * 128 + ko);
      acc[t] = __builtin_amdgcn_mfma_f32_16x16x32_bf16(a, bf, acc[t], 0, 0, 0);
    }
  }

  int rbase = rw + quad * 4;
  int4 mi = *(const int4*)(mask + rbase);
  float mk[4] = {mi.x ? 1.f : 0.f, mi.y ? 1.f : 0.f, mi.z ? 1.f : 0.f, mi.w ? 1.f : 0.f};
#pragma unroll
  for (int t = 0; t < 8; t++) {
    int c = t * 16 + qm;
    float bG = bc[512 + c];
#pragma unroll
    for (int reg = 0; reg < 4; reg++) {
      float g = sigmoidf(acc[t][reg] + bG) * mk[reg];
      gate_out[(size_t)(rbase + reg) * 128 + c] = g;
    }
  }
}

// ---------------------------------------------------------------------------
// K2: tri[d] = To_d (512x512) @ From_d^T, 128 batched NT GEMMs.
// 128x128 tile/block, BK=64, global_load_lds(16B) staging, 4 waves x (4x4)
// MFMA accs. Epilogue repacks C through padded LDS -> dwordx4 stores.
// ---------------------------------------------------------------------------
__global__ __launch_bounds__(256) void tri_gemm_kernel(
    const unsigned short* __restrict__ toT, const unsigned short* __restrict__ fromT,
    unsigned short* __restrict__ triT) {
  __shared__ unsigned short smem[128 * 136]; // K-loop: As=[0,8192) Bs=[8192,16384); epilogue: C 128x136
  unsigned short* As = smem;
  unsigned short* Bs = smem + 128 * 64;

  int d = blockIdx.z;
  int i0 = blockIdx.x * 128, j0 = blockIdx.y * 128;
  int tid = threadIdx.x, w = tid >> 6, lane = tid & 63;
  int qm = lane & 15, quad = lane >> 4;
  int wm = w >> 1, wn = w & 1;
  const unsigned short* A = toT + (size_t)d * RTOT;
  const unsigned short* B = fromT + (size_t)d * RTOT;
  int lr = lane >> 3, lk = (lane & 7) * 8;

  f32x4 acc[4][4];
#pragma unroll
  for (int m = 0; m < 4; m++)
#pragma unroll
    for (int n = 0; n < 4; n++) acc[m][n] = (f32x4){0.f, 0.f, 0.f, 0.f};

  for (int kb = 0; kb < 512; kb += 64) {
    __syncthreads(); // prev compute done reading LDS
#pragma unroll
    for (int q = 0; q < 4; q++) {
      int blk = w * 4 + q; // 16 row-blocks of 8 rows each
      async16(A + (size_t)(i0 + blk * 8 + lr) * 512 + kb + lk, As + blk * 512);
      async16(B + (size_t)(j0 + blk * 8 + lr) * 512 + kb + lk, Bs + blk * 512);
    }
    __syncthreads(); // loads drained (compiler emits vmcnt(0) before barrier)
#pragma unroll
    for (int kk = 0; kk < 2; kk++) {
      bf16x8 af[4], bfr[4];
#pragma unroll
      for (int m = 0; m < 4; m++)
        af[m] = *(const bf16x8*)(As + (wm * 64 + m * 16 + qm) * 64 + kk * 32 + quad * 8);
#pragma unroll
      for (int n = 0; n < 4; n++)
        bfr[n] = *(const bf16x8*)(Bs + (wn * 64 + n * 16 + qm) * 64 + kk * 32 + quad * 8);
#pragma unroll
      for (int m = 0; m < 4; m++)
#pragma unroll
        for (int n = 0; n < 4; n++)
          acc[m][n] = __builtin_amdgcn_mfma_f32_16x16x32_bf16(af[m], bfr[n], acc[m][n], 0, 0, 0);
    }
  }

  __syncthreads(); // done with As/Bs; reuse smem as C 128x136 (pad keeps 16B align, kills conflicts)
#pragma unroll
  for (int m = 0; m < 4; m++) {
    int rb = wm * 64 + m * 16 + quad * 4;
#pragma unroll
    for (int n = 0; n < 4; n++) {
      int col = wn * 64 + n * 16 + qm;
#pragma unroll
      for (int reg = 0; reg < 4; reg++)
        smem[(rb + reg) * 136 + col] = f2bf(acc[m][n][reg]);
    }
  }
  __syncthreads();
  { // each (row, half) copies its FULL 64-short half: 8 x uint4
    int row = tid >> 1, half = tid & 1;
    const uint4* src = (const uint4*)(smem + row * 136 + half * 64);
    uint4 v[8];
#pragma unroll
    for (int u = 0; u < 8; u++) v[u] = src[u];
    uint4* dst = (uint4*)(triT + (size_t)d * RTOT + (size_t)(i0 + row) * 512 + j0 + half * 64);
#pragma unroll
    for (int u = 0; u < 8; u++) dst[u] = v[u];
  }
}

// ---------------------------------------------------------------------------
// K3: LN2 over d=128 of tri (channel-major input), @ W_out^T + b_out, * gate.
// fuse==1: recompute gate in-register from xb (go GEMM fused; d_out write-only).
// fuse==0: legacy path, gate pre-stored fp32 in d_out (RMW).
// ---------------------------------------------------------------------------
__global__ __launch_bounds__(256) void out_kernel(
    const unsigned short* __restrict__ triT, const unsigned short* __restrict__ Woutb,
    const float* __restrict__ ln2w, const float* __restrict__ ln2b,
    const float* __restrict__ b_out, float* __restrict__ out,
    const unsigned short* __restrict__ xb, const unsigned short* __restrict__ Wc,
    const float* __restrict__ bc, const int* __restrict__ mask, int fuse) {
  __shared__ unsigned short nt[64][136];
  __shared__ float mu_s[64], rs_s[64];
  int r0 = blockIdx.x * 64;
  int tid = threadIdx.x;

  { // stage 64 rows x 128 ch, transposing channel-major -> row-major
    int dch = tid >> 1, half = tid & 1;
    const uint4* src = (const uint4*)(triT + (size_t)dch * RTOT + r0 + half * 32);
    uint4 v[4];
    v[0] = src[0]; v[1] = src[1]; v[2] = src[2]; v[3] = src[3];
    const unsigned short* pv = (const unsigned short*)v;
#pragma unroll
    for (int u = 0; u < 32; u++) nt[half * 32 + u][dch] = pv[u];
  }
  __syncthreads();

  { // LN2 stats: 4 lanes per position
    int p = tid >> 2, part = tid & 3;
    float s = 0.f, sq = 0.f;
#pragma unroll
    for (int u = 0; u < 4; u++) {
      bf16x8 v = *(const bf16x8*)(&nt[p][part * 32 + u * 8]);
#pragma unroll
      for (int e = 0; e < 8; e++) {
        float f = bf2f((unsigned short)v[e]);
        s += f; sq += f * f;
      }
    }
    s += __shfl_xor(s, 1); sq += __shfl_xor(sq, 1);
    s += __shfl_xor(s, 2); sq += __shfl_xor(sq, 2);
    float mu = s * (1.f / 128.f);
    float var = sq * (1.f / 128.f) - mu * mu;
    if (part == 0) { mu_s[p] = mu; rs_s[p] = rsqrtf(var + 1e-5f); }
  }
  __syncthreads();

  int wv = tid >> 6, lane = tid & 63;
  int qm = lane & 15, quad = lane >> 4;
  int p = wv * 16 + qm;
  float mu = mu_s[p], rs = rs_s[p];

  bf16x8 afr[4];
#pragma unroll
  for (int kk = 0; kk < 4; kk++) { // build normalized A-fragments
    int ko = kk * 32 + quad * 8;
    bf16x8 raw = *(const bf16x8*)(&nt[p][ko]);
#pragma unroll
    for (int e = 0; e < 8; e++) {
      float wf = ln2w[ko + e], bv = ln2b[ko + e];
      afr[kk][e] = (short)f2bf((bf2f((unsigned short)raw[e]) - mu) * rs * wf + bv);
    }
  }

  f32x4 acc[8];
#pragma unroll
  for (int t = 0; t < 8; t++) acc[t] = (f32x4){0.f, 0.f, 0.f, 0.f};
#pragma unroll
  for (int kk = 0; kk < 4; kk++) {
    int ko = kk * 32 + quad * 8;
#pragma unroll
    for (int t = 0; t < 8; t++) {
      bf16x8 bf = *(const bf16x8*)(Woutb + (size_t)(t * 16 + qm) * 128 + ko);
      acc[t] = __builtin_amdgcn_mfma_f32_16x16x32_bf16(afr[kk], bf, acc[t], 0, 0, 0);
    }
  }

  int rbase = r0 + wv * 16 + quad * 4;
  if (fuse) {
    // fused out_gate: acc2 = xb @ W_go^T (same fragment geometry as go_gemm)
    f32x4 acc2[8];
#pragma unroll
    for (int t = 0; t < 8; t++) acc2[t] = (f32x4){0.f, 0.f, 0.f, 0.f};
    const unsigned short* xrow = xb + (size_t)(r0 + wv * 16 + qm) * 128;
#pragma unroll
    for (int kk = 0; kk < 4; kk++) {
      int ko = kk * 32 + quad * 8;
      bf16x8 a2 = *(const bf16x8*)(xrow + ko);
#pragma unroll
      for (int t = 0; t < 8; t++) {
        bf16x8 bf = *(const bf16x8*)(Wc + (size_t)(512 + t * 16 + qm) * 128 + ko);
        acc2[t] = __builtin_amdgcn_mfma_f32_16x16x32_bf16(a2, bf, acc2[t], 0, 0, 0);
      }
    }
    int4 mi = *(const int4*)(mask + rbase);
    float mk[4] = {mi.x ? 1.f : 0.f, mi.y ? 1.f : 0.f, mi.z ? 1.f : 0.f, mi.w ? 1.f : 0.f};
#pragma unroll
    for (int t = 0; t < 8; t++) {
      int c = t * 16 + qm;
      float bo = b_out[c];
      float bG = bc[512 + c];
#pragma unroll
      for (int reg = 0; reg < 4; reg++) {
        float g = sigmoidf(acc2[t][reg] + bG) * mk[reg];
        out[(size_t)(rbase + reg) * 128 + c] = (acc[t][reg] + bo) * g;
      }
    }
  } else {
#pragma unroll
    for (int t = 0; t < 8; t++) {
      int c = t * 16 + qm;
      float bo = b_out[c];
#pragma unroll
      for (int reg = 0; reg < 4; reg++) {
        size_t off = (size_t)(rbase + reg) * 128 + c;
        out[off] = (acc[t][reg] + bo) * out[off]; // out[] currently holds gate
      }
    }
  }
}

// ---------------------------------------------------------------------------
extern "C" void kernel_launch(void* const* d_in, const int* in_sizes, int n_in,
                              void* d_out, int out_size, void* d_ws, size_t ws_size,
                              hipStream_t stream) {
  const float* edges = (const float*)d_in[0];
  const int* mask = (const int*)d_in[1];
  const float* ln1w = (const float*)d_in[2];
  const float* ln1b = (const float*)d_in[3];
  const float* W_fg = (const float*)d_in[4];
  const float* b_fg = (const float*)d_in[5];
  const float* W_go = (const float*)d_in[6];
  const float* b_go = (const float*)d_in[7];
  const float* ln2w = (const float*)d_in[8];
  const float* ln2b = (const float*)d_in[9];
  const float* W_out = (const float*)d_in[10];
  const float* b_out = (const float*)d_in[11];

  char* ws = (char*)d_ws;
  const size_t SZ = (size_t)RTOT * DCH * 2; // 64 MiB per bf16 buffer
  const size_t WSMALL = 0x40000;            // 256 KiB: Wc(160K)+bc(2.5K)+Woutb(32K), padded
  unsigned short* xb = (unsigned short*)ws;
  unsigned short* toT = (unsigned short*)(ws + SZ);
  unsigned short* fromT = (unsigned short*)(ws + 2 * SZ);
  unsigned short* Wc = (unsigned short*)(ws + 3 * SZ);
  float* bc = (float*)(ws + 3 * SZ + 640 * 128 * 2);
  unsigned short* Woutb = (unsigned short*)(ws + 3 * SZ + 640 * 128 * 2 + 640 * 4);
  float* gate = (float*)d_out;

  // If workspace allows, give triT its own buffer so xb survives -> fuse the
  // gate GEMM into out_kernel (kills 256 MiB of fp32 gate traffic + 1 launch).
  bool fits = ws_size >= 4 * SZ + WSMALL;
  unsigned short* triT = fits ? (unsigned short*)(ws + 3 * SZ + WSMALL) : xb;

  prep_kernel<<<384, 256, 0, stream>>>(W_fg, b_fg, W_go, b_go, W_out, Wc, bc, Woutb);
  ln1_kernel<<<RTOT / 4, 256, 0, stream>>>(edges, ln1w, ln1b, xb);
  fg_gemm_kernel<<<dim3(RTOT / 64, 2), 256, 0, stream>>>(xb, Wc, bc, mask, toT, fromT);
  if (!fits) go_gemm_kernel<<<RTOT / 64, 256, 0, stream>>>(xb, Wc, bc, mask, gate);
  tri_gemm_kernel<<<dim3(4, 4, 128), 256, 0, stream>>>(toT, fromT, triT);
  out_kernel<<<RTOT / 64, 256, 0, stream>>>(triT, Woutb, ln2w, ln2b, b_out,
                                            (float*)d_out, xb, Wc, bc, mask, fits ? 1 : 0);
}

// Round 4
// 619.196 us; speedup vs baseline: 1.2217x; 1.0100x over previous
//
#include <hip/hip_runtime.h>

#define NSEQ 512
#define DCH 128
#define RTOT (NSEQ * NSEQ) /* 262144 */

typedef __attribute__((ext_vector_type(8))) short bf16x8;
typedef __attribute__((ext_vector_type(4))) float f32x4;

__device__ __forceinline__ unsigned short f2bf(float v) {
  union { float f; unsigned int u; } x; x.f = v;
  unsigned int u = x.u;
  return (unsigned short)((u + 0x7fffu + ((u >> 16) & 1u)) >> 16);
}
__device__ __forceinline__ float bf2f(unsigned short s) {
  union { unsigned int u; float f; } x; x.u = ((unsigned int)s) << 16;
  return x.f;
}
__device__ __forceinline__ float sigmoidf(float x) { return 1.f / (1.f + __expf(-x)); }

// async global->LDS, 16B per lane; LDS dst is wave-uniform base (+ lane*16 implicit)
__device__ __forceinline__ void async16(const unsigned short* g, unsigned short* l) {
  __builtin_amdgcn_global_load_lds(
      (const __attribute__((address_space(1))) unsigned int*)g,
      (__attribute__((address_space(3))) unsigned int*)l, 16, 0, 0);
}

// ---------------------------------------------------------------------------
// prep: pack weights (reordered) into bf16.  Wc rows: [0,128)=to-feat,
// [128,256)=to-gate, [256,384)=from-feat, [384,512)=from-gate, [512,640)=go.
// ---------------------------------------------------------------------------
__global__ void prep_kernel(const float* __restrict__ W_fg, const float* __restrict__ b_fg,
                            const float* __restrict__ W_go, const float* __restrict__ b_go,
                            const float* __restrict__ W_out,
                            unsigned short* __restrict__ Wc, float* __restrict__ bc,
                            unsigned short* __restrict__ Woutb) {
  int idx = blockIdx.x * 256 + threadIdx.x;
  if (idx < 640 * 128) {
    int rr = idx >> 7, k = idx & 127;
    float v, bv;
    if (rr < 512) {
      int m = rr >> 7;
      int srow = (m == 1) ? rr + 128 : (m == 2) ? rr - 128 : rr;
      v = W_fg[srow * 128 + k];
      bv = b_fg[srow];
    } else {
      int srow = rr - 512;
      v = W_go[srow * 128 + k];
      bv = b_go[srow];
    }
    Wc[idx] = f2bf(v);
    if (k == 0) bc[rr] = bv;
  } else {
    int i2 = idx - 640 * 128;
    if (i2 < 128 * 128) Woutb[i2] = f2bf(W_out[i2]);
  }
}

// ---------------------------------------------------------------------------
// K0: LayerNorm over last dim (128) of edges; write x as bf16. 1 wave = 1 row.
// ---------------------------------------------------------------------------
__global__ __launch_bounds__(256) void ln1_kernel(const float* __restrict__ edges,
                                                  const float* __restrict__ w,
                                                  const float* __restrict__ b,
                                                  unsigned short* __restrict__ xb) {
  int wv = threadIdx.x >> 6;
  int lane = threadIdx.x & 63;
  size_t row = (size_t)blockIdx.x * 4 + wv;
  const float2* e = (const float2*)(edges + row * 128);
  float2 v = e[lane];
  float s = v.x + v.y, sq = v.x * v.x + v.y * v.y;
#pragma unroll
  for (int off = 32; off; off >>= 1) {
    s += __shfl_xor(s, off);
    sq += __shfl_xor(sq, off);
  }
  float mu = s * (1.f / 128.f);
  float var = sq * (1.f / 128.f) - mu * mu;
  float rs = rsqrtf(var + 1e-5f);
  int c = lane * 2;
  float x0 = (v.x - mu) * rs * w[c] + b[c];
  float x1 = (v.y - mu) * rs * w[c + 1] + b[c + 1];
  unsigned int packed = (unsigned int)f2bf(x0) | ((unsigned int)f2bf(x1) << 16);
  ((unsigned int*)(xb + row * 128))[lane] = packed;
}

// ---------------------------------------------------------------------------
// K1a: fg GEMM + gating + mask.  Col-split waves, B fragments hoisted into
// registers (Wc block-invariant).  LDS transpose epilogue -> 128B-line stores.
// ---------------------------------------------------------------------------
__global__ __launch_bounds__(256) void fg_gemm_kernel(
    const unsigned short* __restrict__ xb, const unsigned short* __restrict__ Wc,
    const float* __restrict__ bc, const int* __restrict__ mask,
    unsigned short* __restrict__ toT, unsigned short* __restrict__ fromT) {
  __shared__ unsigned int Cs[128 * 36]; // 128 planes x 64 rows bf16 (pad 36 uints/plane)
  int nb = blockIdx.y;
  int wv = threadIdx.x >> 6, lane = threadIdx.x & 63;
  int qm = lane & 15, quad = lane >> 4;
  int r0 = blockIdx.x * 64;
  int nbase = nb * 256;

  // Hoisted B fragments: feat cols nbase+wv*32+ft*16, gate cols +128.
  bf16x8 Bf[2][4], Bg[2][4];
#pragma unroll
  for (int ft = 0; ft < 2; ft++)
#pragma unroll
    for (int kk = 0; kk < 4; kk++) {
      int ko = kk * 32 + quad * 8;
      Bf[ft][kk] = *(const bf16x8*)(Wc + (size_t)(nbase + wv * 32 + ft * 16 + qm) * 128 + ko);
      Bg[ft][kk] = *(const bf16x8*)(Wc + (size_t)(nbase + 128 + wv * 32 + ft * 16 + qm) * 128 + ko);
    }

#pragma unroll
  for (int m = 0; m < 4; m++) { // 4 row-steps of 16 rows
    int rw = r0 + m * 16;
    f32x4 accf[2], accg[2];
#pragma unroll
    for (int ft = 0; ft < 2; ft++) {
      accf[ft] = (f32x4){0.f, 0.f, 0.f, 0.f};
      accg[ft] = (f32x4){0.f, 0.f, 0.f, 0.f};
    }
#pragma unroll
    for (int kk = 0; kk < 4; kk++) {
      int ko = kk * 32 + quad * 8;
      bf16x8 a = *(const bf16x8*)(xb + (size_t)(rw + qm) * 128 + ko);
#pragma unroll
      for (int ft = 0; ft < 2; ft++) {
        accf[ft] = __builtin_amdgcn_mfma_f32_16x16x32_bf16(a, Bf[ft][kk], accf[ft], 0, 0, 0);
        accg[ft] = __builtin_amdgcn_mfma_f32_16x16x32_bf16(a, Bg[ft][kk], accg[ft], 0, 0, 0);
      }
    }
    int rbase = rw + quad * 4;
    int4 mi = *(const int4*)(mask + rbase);
    float mk[4] = {mi.x ? 1.f : 0.f, mi.y ? 1.f : 0.f, mi.z ? 1.f : 0.f, mi.w ? 1.f : 0.f};
#pragma unroll
    for (int ft = 0; ft < 2; ft++) {
      int c = wv * 32 + ft * 16 + qm; // local col 0..127
      float bF = bc[nbase + c];
      float bG = bc[nbase + 128 + c];
      float v0 = (accf[ft][0] + bF) * sigmoidf(accg[ft][0] + bG) * mk[0];
      float v1 = (accf[ft][1] + bF) * sigmoidf(accg[ft][1] + bG) * mk[1];
      float v2 = (accf[ft][2] + bF) * sigmoidf(accg[ft][2] + bG) * mk[2];
      float v3 = (accf[ft][3] + bF) * sigmoidf(accg[ft][3] + bG) * mk[3];
      unsigned int u0 = (unsigned int)f2bf(v0) | ((unsigned int)f2bf(v1) << 16);
      unsigned int u1 = (unsigned int)f2bf(v2) | ((unsigned int)f2bf(v3) << 16);
      *(uint2*)(Cs + c * 36 + m * 8 + quad * 2) = (uint2){u0, u1};
    }
  }
  __syncthreads();
  { // wave writes its own 32 planes; 8 lanes/plane -> 128B contiguous lines
    unsigned short* dst = (nb == 0) ? toT : fromT;
    int pl = lane >> 3, lo = lane & 7;
#pragma unroll
    for (int i = 0; i < 4; i++) {
      int p = wv * 32 + i * 8 + pl;
      uint4 v = *(const uint4*)(Cs + p * 36 + lo * 4);
      *(uint4*)(dst + (size_t)p * RTOT + r0 + lo * 8) = v;
    }
  }
}

// ---------------------------------------------------------------------------
// K1b (FALLBACK ONLY, used when workspace too small to de-alias triT):
// out_gate = sigmoid(x @ W_go^T + b_go) * mask, fp32, into d_out.
// ---------------------------------------------------------------------------
__global__ __launch_bounds__(256) void go_gemm_kernel(
    const unsigned short* __restrict__ xb, const unsigned short* __restrict__ Wc,
    const float* __restrict__ bc, const int* __restrict__ mask,
    float* __restrict__ gate_out) {
  int wv = threadIdx.x >> 6, lane = threadIdx.x & 63;
  int qm = lane & 15, quad = lane >> 4;
  int rw = blockIdx.x * 64 + wv * 16;

  f32x4 acc[8];
#pragma unroll
  for (int t = 0; t < 8; t++) acc[t] = (f32x4){0.f, 0.f, 0.f, 0.f};

#pragma unroll
  for (int kk = 0; kk < 4; kk++) {
    int ko = kk * 32 + quad * 8;
    bf16x8 a = *(const bf16x8*)(xb + (size_t)(rw + qm) * 128 + ko);
#pragma unroll
    for (int t = 0; t < 8; t++) {
      bf16x8 bf = *(const bf16x8*)(Wc + (size_t)(512 + t * 16 + qm) * 128 + ko);
      acc[t] = __builtin_amdgcn_mfma_f32_16x16x32_bf16(a, bf, acc[t], 0, 0, 0);
    }
  }

  int rbase = rw + quad * 4;
  int4 mi = *(const int4*)(mask + rbase);
  float mk[4] = {mi.x ? 1.f : 0.f, mi.y ? 1.f : 0.f, mi.z ? 1.f : 0.f, mi.w ? 1.f : 0.f};
#pragma unroll
  for (int t = 0; t < 8; t++) {
    int c = t * 16 + qm;
    float bG = bc[512 + c];
#pragma unroll
    for (int reg = 0; reg < 4; reg++) {
      float g = sigmoidf(acc[t][reg] + bG) * mk[reg];
      gate_out[(size_t)(rbase + reg) * 128 + c] = g;
    }
  }
}

// ---------------------------------------------------------------------------
// K2: tri[d] = To_d (512x512) @ From_d^T, 128 batched NT GEMMs.
// 128x128 tile/block, BK=64, global_load_lds(16B) staging, 4 waves x (4x4)
// MFMA accs. Epilogue repacks C through padded LDS -> dwordx4 stores.
// ---------------------------------------------------------------------------
__global__ __launch_bounds__(256) void tri_gemm_kernel(
    const unsigned short* __restrict__ toT, const unsigned short* __restrict__ fromT,
    unsigned short* __restrict__ triT) {
  __shared__ unsigned short smem[128 * 136]; // K-loop: As=[0,8192) Bs=[8192,16384); epilogue: C 128x136
  unsigned short* As = smem;
  unsigned short* Bs = smem + 128 * 64;

  int d = blockIdx.z;
  int i0 = blockIdx.x * 128, j0 = blockIdx.y * 128;
  int tid = threadIdx.x, w = tid >> 6, lane = tid & 63;
  int qm = lane & 15, quad = lane >> 4;
  int wm = w >> 1, wn = w & 1;
  const unsigned short* A = toT + (size_t)d * RTOT;
  const unsigned short* B = fromT + (size_t)d * RTOT;
  int lr = lane >> 3, lk = (lane & 7) * 8;

  f32x4 acc[4][4];
#pragma unroll
  for (int m = 0; m < 4; m++)
#pragma unroll
    for (int n = 0; n < 4; n++) acc[m][n] = (f32x4){0.f, 0.f, 0.f, 0.f};

  for (int kb = 0; kb < 512; kb += 64) {
    __syncthreads(); // prev compute done reading LDS
#pragma unroll
    for (int q = 0; q < 4; q++) {
      int blk = w * 4 + q; // 16 row-blocks of 8 rows each
      async16(A + (size_t)(i0 + blk * 8 + lr) * 512 + kb + lk, As + blk * 512);
      async16(B + (size_t)(j0 + blk * 8 + lr) * 512 + kb + lk, Bs + blk * 512);
    }
    __syncthreads(); // loads drained (compiler emits vmcnt(0) before barrier)
#pragma unroll
    for (int kk = 0; kk < 2; kk++) {
      bf16x8 af[4], bfr[4];
#pragma unroll
      for (int m = 0; m < 4; m++)
        af[m] = *(const bf16x8*)(As + (wm * 64 + m * 16 + qm) * 64 + kk * 32 + quad * 8);
#pragma unroll
      for (int n = 0; n < 4; n++)
        bfr[n] = *(const bf16x8*)(Bs + (wn * 64 + n * 16 + qm) * 64 + kk * 32 + quad * 8);
#pragma unroll
      for (int m = 0; m < 4; m++)
#pragma unroll
        for (int n = 0; n < 4; n++)
          acc[m][n] = __builtin_amdgcn_mfma_f32_16x16x32_bf16(af[m], bfr[n], acc[m][n], 0, 0, 0);
    }
  }

  __syncthreads(); // done with As/Bs; reuse smem as C 128x136 (pad keeps 16B align, kills conflicts)
#pragma unroll
  for (int m = 0; m < 4; m++) {
    int rb = wm * 64 + m * 16 + quad * 4;
#pragma unroll
    for (int n = 0; n < 4; n++) {
      int col = wn * 64 + n * 16 + qm;
#pragma unroll
      for (int reg = 0; reg < 4; reg++)
        smem[(rb + reg) * 136 + col] = f2bf(acc[m][n][reg]);
    }
  }
  __syncthreads();
  { // each (row, half) copies its FULL 64-short half: 8 x uint4
    int row = tid >> 1, half = tid & 1;
    const uint4* src = (const uint4*)(smem + row * 136 + half * 64);
    uint4 v[8];
#pragma unroll
    for (int u = 0; u < 8; u++) v[u] = src[u];
    uint4* dst = (uint4*)(triT + (size_t)d * RTOT + (size_t)(i0 + row) * 512 + j0 + half * 64);
#pragma unroll
    for (int u = 0; u < 8; u++) dst[u] = v[u];
  }
}

// ---------------------------------------------------------------------------
// K3: LN2 over d=128 of tri (channel-major input), @ W_out^T + b_out, * gate.
// Col-split waves + register-hoisted B fragments (the fg_gemm-proven fix for
// the 64-dependent-L2-loads latency chain).  Staging + stats are the round-2
// proven code (nt stays RAW; mu_s/rs_s in LDS; NO in-place LDS RMW).  A-frags
// normalized on the fly in registers; gate A read direct from global xb.
// ---------------------------------------------------------------------------
__global__ __launch_bounds__(256) void out_kernel(
    const unsigned short* __restrict__ triT, const unsigned short* __restrict__ Woutb,
    const float* __restrict__ ln2w, const float* __restrict__ ln2b,
    const float* __restrict__ b_out, float* __restrict__ out,
    const unsigned short* __restrict__ xb, const unsigned short* __restrict__ Wc,
    const float* __restrict__ bc, const int* __restrict__ mask, int fuse) {
  __shared__ unsigned short nt[64][136];
  __shared__ float mu_s[64], rs_s[64];
  int r0 = blockIdx.x * 64;
  int tid = threadIdx.x;

  { // stage 64 rows x 128 ch, transposing channel-major -> row-major
    int dch = tid >> 1, half = tid & 1;
    const uint4* src = (const uint4*)(triT + (size_t)dch * RTOT + r0 + half * 32);
    uint4 v[4];
    v[0] = src[0]; v[1] = src[1]; v[2] = src[2]; v[3] = src[3];
    const unsigned short* pv = (const unsigned short*)v;
#pragma unroll
    for (int u = 0; u < 32; u++) nt[half * 32 + u][dch] = pv[u];
  }
  __syncthreads();

  { // LN2 stats: 4 lanes per position (round-2 verbatim)
    int p = tid >> 2, part = tid & 3;
    float s = 0.f, sq = 0.f;
#pragma unroll
    for (int u = 0; u < 4; u++) {
      bf16x8 v = *(const bf16x8*)(&nt[p][part * 32 + u * 8]);
#pragma unroll
      for (int e = 0; e < 8; e++) {
        float f = bf2f((unsigned short)v[e]);
        s += f; sq += f * f;
      }
    }
    s += __shfl_xor(s, 1); sq += __shfl_xor(sq, 1);
    s += __shfl_xor(s, 2); sq += __shfl_xor(sq, 2);
    float mu = s * (1.f / 128.f);
    float var = sq * (1.f / 128.f) - mu * mu;
    if (part == 0) { mu_s[p] = mu; rs_s[p] = rsqrtf(var + 1e-5f); }
  }
  __syncthreads();

  int wv = tid >> 6, lane = tid & 63;
  int qm = lane & 15, quad = lane >> 4;

  // Hoisted B fragments for this wave's 32 output cols (fg_gemm-proven pattern).
  bf16x8 Bo[2][4], Bg[2][4];
#pragma unroll
  for (int ft = 0; ft < 2; ft++)
#pragma unroll
    for (int kk = 0; kk < 4; kk++) {
      int c = wv * 32 + ft * 16 + qm;
      int ko = kk * 32 + quad * 8;
      Bo[ft][kk] = *(const bf16x8*)(Woutb + (size_t)c * 128 + ko);
      if (fuse) Bg[ft][kk] = *(const bf16x8*)(Wc + (size_t)(512 + c) * 128 + ko);
    }

#pragma unroll
  for (int m = 0; m < 4; m++) { // 4 row-steps of 16 rows
    int rl = m * 16 + qm;
    float mu = mu_s[rl], rs = rs_s[rl];

    // Build normalized A-fragments in registers (round-2 arithmetic).
    bf16x8 afr[4];
#pragma unroll
    for (int kk = 0; kk < 4; kk++) {
      int ko = kk * 32 + quad * 8;
      bf16x8 raw = *(const bf16x8*)(&nt[rl][ko]);
#pragma unroll
      for (int e = 0; e < 8; e++) {
        float wf = ln2w[ko + e], bv = ln2b[ko + e];
        afr[kk][e] = (short)f2bf((bf2f((unsigned short)raw[e]) - mu) * rs * wf + bv);
      }
    }

    f32x4 accO[2], accG[2];
#pragma unroll
    for (int ft = 0; ft < 2; ft++) {
      accO[ft] = (f32x4){0.f, 0.f, 0.f, 0.f};
      accG[ft] = (f32x4){0.f, 0.f, 0.f, 0.f};
    }
    const unsigned short* xrow = xb + (size_t)(r0 + rl) * 128;
#pragma unroll
    for (int kk = 0; kk < 4; kk++) {
      int ko = kk * 32 + quad * 8;
#pragma unroll
      for (int ft = 0; ft < 2; ft++)
        accO[ft] = __builtin_amdgcn_mfma_f32_16x16x32_bf16(afr[kk], Bo[ft][kk], accO[ft], 0, 0, 0);
      if (fuse) {
        bf16x8 a2 = *(const bf16x8*)(xrow + ko); // global read, round-2-proven path
#pragma unroll
        for (int ft = 0; ft < 2; ft++)
          accG[ft] = __builtin_amdgcn_mfma_f32_16x16x32_bf16(a2, Bg[ft][kk], accG[ft], 0, 0, 0);
      }
    }

    int rbase = r0 + m * 16 + quad * 4;
    if (fuse) {
      int4 mi = *(const int4*)(mask + rbase);
      float mk[4] = {mi.x ? 1.f : 0.f, mi.y ? 1.f : 0.f, mi.z ? 1.f : 0.f, mi.w ? 1.f : 0.f};
#pragma unroll
      for (int ft = 0; ft < 2; ft++) {
        int c = wv * 32 + ft * 16 + qm;
        float bo = b_out[c];
        float bG = bc[512 + c];
#pragma unroll
        for (int reg = 0; reg < 4; reg++) {
          float g = sigmoidf(accG[ft][reg] + bG) * mk[reg];
          out[(size_t)(rbase + reg) * 128 + c] = (accO[ft][reg] + bo) * g;
        }
      }
    } else {
#pragma unroll
      for (int ft = 0; ft < 2; ft++) {
        int c = wv * 32 + ft * 16 + qm;
        float bo = b_out[c];
#pragma unroll
        for (int reg = 0; reg < 4; reg++) {
          size_t off = (size_t)(rbase + reg) * 128 + c;
          out[off] = (accO[ft][reg] + bo) * out[off]; // out[] holds gate
        }
      }
    }
  }
}

// ---------------------------------------------------------------------------
extern "C" void kernel_launch(void* const* d_in, const int* in_sizes, int n_in,
                              void* d_out, int out_size, void* d_ws, size_t ws_size,
                              hipStream_t stream) {
  const float* edges = (const float*)d_in[0];
  const int* mask = (const int*)d_in[1];
  const float* ln1w = (const float*)d_in[2];
  const float* ln1b = (const float*)d_in[3];
  const float* W_fg = (const float*)d_in[4];
  const float* b_fg = (const float*)d_in[5];
  const float* W_go = (const float*)d_in[6];
  const float* b_go = (const float*)d_in[7];
  const float* ln2w = (const float*)d_in[8];
  const float* ln2b = (const float*)d_in[9];
  const float* W_out = (const float*)d_in[10];
  const float* b_out = (const float*)d_in[11];

  char* ws = (char*)d_ws;
  const size_t SZ = (size_t)RTOT * DCH * 2; // 64 MiB per bf16 buffer
  const size_t WSMALL = 0x40000;            // 256 KiB: Wc(160K)+bc(2.5K)+Woutb(32K), padded
  unsigned short* xb = (unsigned short*)ws;
  unsigned short* toT = (unsigned short*)(ws + SZ);
  unsigned short* fromT = (unsigned short*)(ws + 2 * SZ);
  unsigned short* Wc = (unsigned short*)(ws + 3 * SZ);
  float* bc = (float*)(ws + 3 * SZ + 640 * 128 * 2);
  unsigned short* Woutb = (unsigned short*)(ws + 3 * SZ + 640 * 128 * 2 + 640 * 4);
  float* gate = (float*)d_out;

  // If workspace allows, give triT its own buffer so xb survives -> fuse the
  // gate GEMM into out_kernel (kills 256 MiB of fp32 gate traffic + 1 launch).
  bool fits = ws_size >= 4 * SZ + WSMALL;
  unsigned short* triT = fits ? (unsigned short*)(ws + 3 * SZ + WSMALL) : xb;

  prep_kernel<<<384, 256, 0, stream>>>(W_fg, b_fg, W_go, b_go, W_out, Wc, bc, Woutb);
  ln1_kernel<<<RTOT / 4, 256, 0, stream>>>(edges, ln1w, ln1b, xb);
  fg_gemm_kernel<<<dim3(RTOT / 64, 2), 256, 0, stream>>>(xb, Wc, bc, mask, toT, fromT);
  if (!fits) go_gemm_kernel<<<RTOT / 64, 256, 0, stream>>>(xb, Wc, bc, mask, gate);
  tri_gemm_kernel<<<dim3(4, 4, 128), 256, 0, stream>>>(toT, fromT, triT);
  out_kernel<<<RTOT / 64, 256, 0, stream>>>(triT, Woutb, ln2w, ln2b, b_out,
                                            (float*)d_out, xb, Wc, bc, mask, fits ? 1 : 0);
}

// Round 5
// 595.419 us; speedup vs baseline: 1.2705x; 1.0399x over previous
//
#include <hip/hip_runtime.h>

#define NSEQ 512
#define DCH 128
#define RTOT (NSEQ * NSEQ) /* 262144 */

typedef __attribute__((ext_vector_type(8))) short bf16x8;
typedef __attribute__((ext_vector_type(4))) float f32x4;

__device__ __forceinline__ unsigned short f2bf(float v) {
  union { float f; unsigned int u; } x; x.f = v;
  unsigned int u = x.u;
  return (unsigned short)((u + 0x7fffu + ((u >> 16) & 1u)) >> 16);
}
__device__ __forceinline__ float bf2f(unsigned short s) {
  union { unsigned int u; float f; } x; x.u = ((unsigned int)s) << 16;
  return x.f;
}
__device__ __forceinline__ float sigmoidf(float x) { return 1.f / (1.f + __expf(-x)); }

// async global->LDS, 16B per lane; LDS dst is wave-uniform base (+ lane*16 implicit)
__device__ __forceinline__ void async16(const unsigned short* g, unsigned short* l) {
  __builtin_amdgcn_global_load_lds(
      (const __attribute__((address_space(1))) unsigned int*)g,
      (__attribute__((address_space(3))) unsigned int*)l, 16, 0, 0);
}

// ---------------------------------------------------------------------------
// prep: pack weights (reordered) into bf16.  Wc rows: [0,128)=to-feat,
// [128,256)=to-gate, [256,384)=from-feat, [384,512)=from-gate, [512,640)=go.
// ---------------------------------------------------------------------------
__global__ void prep_kernel(const float* __restrict__ W_fg, const float* __restrict__ b_fg,
                            const float* __restrict__ W_go, const float* __restrict__ b_go,
                            const float* __restrict__ W_out,
                            unsigned short* __restrict__ Wc, float* __restrict__ bc,
                            unsigned short* __restrict__ Woutb) {
  int idx = blockIdx.x * 256 + threadIdx.x;
  if (idx < 640 * 128) {
    int rr = idx >> 7, k = idx & 127;
    float v, bv;
    if (rr < 512) {
      int m = rr >> 7;
      int srow = (m == 1) ? rr + 128 : (m == 2) ? rr - 128 : rr;
      v = W_fg[srow * 128 + k];
      bv = b_fg[srow];
    } else {
      int srow = rr - 512;
      v = W_go[srow * 128 + k];
      bv = b_go[srow];
    }
    Wc[idx] = f2bf(v);
    if (k == 0) bc[rr] = bv;
  } else {
    int i2 = idx - 640 * 128;
    if (i2 < 128 * 128) Woutb[i2] = f2bf(W_out[i2]);
  }
}

// ---------------------------------------------------------------------------
// K0: LayerNorm over last dim (128) of edges; write x as bf16. 1 wave = 1 row.
// ---------------------------------------------------------------------------
__global__ __launch_bounds__(256) void ln1_kernel(const float* __restrict__ edges,
                                                  const float* __restrict__ w,
                                                  const float* __restrict__ b,
                                                  unsigned short* __restrict__ xb) {
  int wv = threadIdx.x >> 6;
  int lane = threadIdx.x & 63;
  size_t row = (size_t)blockIdx.x * 4 + wv;
  const float2* e = (const float2*)(edges + row * 128);
  float2 v = e[lane];
  float s = v.x + v.y, sq = v.x * v.x + v.y * v.y;
#pragma unroll
  for (int off = 32; off; off >>= 1) {
    s += __shfl_xor(s, off);
    sq += __shfl_xor(sq, off);
  }
  float mu = s * (1.f / 128.f);
  float var = sq * (1.f / 128.f) - mu * mu;
  float rs = rsqrtf(var + 1e-5f);
  int c = lane * 2;
  float x0 = (v.x - mu) * rs * w[c] + b[c];
  float x1 = (v.y - mu) * rs * w[c + 1] + b[c + 1];
  unsigned int packed = (unsigned int)f2bf(x0) | ((unsigned int)f2bf(x1) << 16);
  ((unsigned int*)(xb + row * 128))[lane] = packed;
}

// ---------------------------------------------------------------------------
// K1a: fg GEMM + gating + mask.  Col-split waves, B fragments hoisted into
// registers (Wc block-invariant).  LDS transpose epilogue -> 128B-line stores.
// ---------------------------------------------------------------------------
__global__ __launch_bounds__(256) void fg_gemm_kernel(
    const unsigned short* __restrict__ xb, const unsigned short* __restrict__ Wc,
    const float* __restrict__ bc, const int* __restrict__ mask,
    unsigned short* __restrict__ toT, unsigned short* __restrict__ fromT) {
  __shared__ unsigned int Cs[128 * 36]; // 128 planes x 64 rows bf16 (pad 36 uints/plane)
  int nb = blockIdx.y;
  int wv = threadIdx.x >> 6, lane = threadIdx.x & 63;
  int qm = lane & 15, quad = lane >> 4;
  int r0 = blockIdx.x * 64;
  int nbase = nb * 256;

  // Hoisted B fragments: feat cols nbase+wv*32+ft*16, gate cols +128.
  bf16x8 Bf[2][4], Bg[2][4];
#pragma unroll
  for (int ft = 0; ft < 2; ft++)
#pragma unroll
    for (int kk = 0; kk < 4; kk++) {
      int ko = kk * 32 + quad * 8;
      Bf[ft][kk] = *(const bf16x8*)(Wc + (size_t)(nbase + wv * 32 + ft * 16 + qm) * 128 + ko);
      Bg[ft][kk] = *(const bf16x8*)(Wc + (size_t)(nbase + 128 + wv * 32 + ft * 16 + qm) * 128 + ko);
    }

#pragma unroll
  for (int m = 0; m < 4; m++) { // 4 row-steps of 16 rows
    int rw = r0 + m * 16;
    f32x4 accf[2], accg[2];
#pragma unroll
    for (int ft = 0; ft < 2; ft++) {
      accf[ft] = (f32x4){0.f, 0.f, 0.f, 0.f};
      accg[ft] = (f32x4){0.f, 0.f, 0.f, 0.f};
    }
#pragma unroll
    for (int kk = 0; kk < 4; kk++) {
      int ko = kk * 32 + quad * 8;
      bf16x8 a = *(const bf16x8*)(xb + (size_t)(rw + qm) * 128 + ko);
#pragma unroll
      for (int ft = 0; ft < 2; ft++) {
        accf[ft] = __builtin_amdgcn_mfma_f32_16x16x32_bf16(a, Bf[ft][kk], accf[ft], 0, 0, 0);
        accg[ft] = __builtin_amdgcn_mfma_f32_16x16x32_bf16(a, Bg[ft][kk], accg[ft], 0, 0, 0);
      }
    }
    int rbase = rw + quad * 4;
    int4 mi = *(const int4*)(mask + rbase);
    float mk[4] = {mi.x ? 1.f : 0.f, mi.y ? 1.f : 0.f, mi.z ? 1.f : 0.f, mi.w ? 1.f : 0.f};
#pragma unroll
    for (int ft = 0; ft < 2; ft++) {
      int c = wv * 32 + ft * 16 + qm; // local col 0..127
      float bF = bc[nbase + c];
      float bG = bc[nbase + 128 + c];
      float v0 = (accf[ft][0] + bF) * sigmoidf(accg[ft][0] + bG) * mk[0];
      float v1 = (accf[ft][1] + bF) * sigmoidf(accg[ft][1] + bG) * mk[1];
      float v2 = (accf[ft][2] + bF) * sigmoidf(accg[ft][2] + bG) * mk[2];
      float v3 = (accf[ft][3] + bF) * sigmoidf(accg[ft][3] + bG) * mk[3];
      unsigned int u0 = (unsigned int)f2bf(v0) | ((unsigned int)f2bf(v1) << 16);
      unsigned int u1 = (unsigned int)f2bf(v2) | ((unsigned int)f2bf(v3) << 16);
      *(uint2*)(Cs + c * 36 + m * 8 + quad * 2) = (uint2){u0, u1};
    }
  }
  __syncthreads();
  { // wave writes its own 32 planes; 8 lanes/plane -> 128B contiguous lines
    unsigned short* dst = (nb == 0) ? toT : fromT;
    int pl = lane >> 3, lo = lane & 7;
#pragma unroll
    for (int i = 0; i < 4; i++) {
      int p = wv * 32 + i * 8 + pl;
      uint4 v = *(const uint4*)(Cs + p * 36 + lo * 4);
      *(uint4*)(dst + (size_t)p * RTOT + r0 + lo * 8) = v;
    }
  }
}

// ---------------------------------------------------------------------------
// K1b (FALLBACK ONLY, used when workspace too small to de-alias triT):
// out_gate = sigmoid(x @ W_go^T + b_go) * mask, fp32, into d_out.
// ---------------------------------------------------------------------------
__global__ __launch_bounds__(256) void go_gemm_kernel(
    const unsigned short* __restrict__ xb, const unsigned short* __restrict__ Wc,
    const float* __restrict__ bc, const int* __restrict__ mask,
    float* __restrict__ gate_out) {
  int wv = threadIdx.x >> 6, lane = threadIdx.x & 63;
  int qm = lane & 15, quad = lane >> 4;
  int rw = blockIdx.x * 64 + wv * 16;

  f32x4 acc[8];
#pragma unroll
  for (int t = 0; t < 8; t++) acc[t] = (f32x4){0.f, 0.f, 0.f, 0.f};

#pragma unroll
  for (int kk = 0; kk < 4; kk++) {
    int ko = kk * 32 + quad * 8;
    bf16x8 a = *(const bf16x8*)(xb + (size_t)(rw + qm) * 128 + ko);
#pragma unroll
    for (int t = 0; t < 8; t++) {
      bf16x8 bf = *(const bf16x8*)(Wc + (size_t)(512 + t * 16 + qm) * 128 + ko);
      acc[t] = __builtin_amdgcn_mfma_f32_16x16x32_bf16(a, bf, acc[t], 0, 0, 0);
    }
  }

  int rbase = rw + quad * 4;
  int4 mi = *(const int4*)(mask + rbase);
  float mk[4] = {mi.x ? 1.f : 0.f, mi.y ? 1.f : 0.f, mi.z ? 1.f : 0.f, mi.w ? 1.f : 0.f};
#pragma unroll
  for (int t = 0; t < 8; t++) {
    int c = t * 16 + qm;
    float bG = bc[512 + c];
#pragma unroll
    for (int reg = 0; reg < 4; reg++) {
      float g = sigmoidf(acc[t][reg] + bG) * mk[reg];
      gate_out[(size_t)(rbase + reg) * 128 + c] = g;
    }
  }
}

// ---------------------------------------------------------------------------
// K2: tri[d] = To_d (512x512) @ From_d^T, 128 batched NT GEMMs.
// 128x128 tile/block, BK=64, global_load_lds(16B) staging, 4 waves x (4x4)
// MFMA accs. Epilogue repacks C through padded LDS -> dwordx4 stores.
// ---------------------------------------------------------------------------
__global__ __launch_bounds__(256) void tri_gemm_kernel(
    const unsigned short* __restrict__ toT, const unsigned short* __restrict__ fromT,
    unsigned short* __restrict__ triT) {
  __shared__ unsigned short smem[128 * 136]; // K-loop: As=[0,8192) Bs=[8192,16384); epilogue: C 128x136
  unsigned short* As = smem;
  unsigned short* Bs = smem + 128 * 64;

  int d = blockIdx.z;
  int i0 = blockIdx.x * 128, j0 = blockIdx.y * 128;
  int tid = threadIdx.x, w = tid >> 6, lane = tid & 63;
  int qm = lane & 15, quad = lane >> 4;
  int wm = w >> 1, wn = w & 1;
  const unsigned short* A = toT + (size_t)d * RTOT;
  const unsigned short* B = fromT + (size_t)d * RTOT;
  int lr = lane >> 3, lk = (lane & 7) * 8;

  f32x4 acc[4][4];
#pragma unroll
  for (int m = 0; m < 4; m++)
#pragma unroll
    for (int n = 0; n < 4; n++) acc[m][n] = (f32x4){0.f, 0.f, 0.f, 0.f};

  for (int kb = 0; kb < 512; kb += 64) {
    __syncthreads(); // prev compute done reading LDS
#pragma unroll
    for (int q = 0; q < 4; q++) {
      int blk = w * 4 + q; // 16 row-blocks of 8 rows each
      async16(A + (size_t)(i0 + blk * 8 + lr) * 512 + kb + lk, As + blk * 512);
      async16(B + (size_t)(j0 + blk * 8 + lr) * 512 + kb + lk, Bs + blk * 512);
    }
    __syncthreads(); // loads drained (compiler emits vmcnt(0) before barrier)
#pragma unroll
    for (int kk = 0; kk < 2; kk++) {
      bf16x8 af[4], bfr[4];
#pragma unroll
      for (int m = 0; m < 4; m++)
        af[m] = *(const bf16x8*)(As + (wm * 64 + m * 16 + qm) * 64 + kk * 32 + quad * 8);
#pragma unroll
      for (int n = 0; n < 4; n++)
        bfr[n] = *(const bf16x8*)(Bs + (wn * 64 + n * 16 + qm) * 64 + kk * 32 + quad * 8);
#pragma unroll
      for (int m = 0; m < 4; m++)
#pragma unroll
        for (int n = 0; n < 4; n++)
          acc[m][n] = __builtin_amdgcn_mfma_f32_16x16x32_bf16(af[m], bfr[n], acc[m][n], 0, 0, 0);
    }
  }

  __syncthreads(); // done with As/Bs; reuse smem as C 128x136 (pad keeps 16B align, kills conflicts)
#pragma unroll
  for (int m = 0; m < 4; m++) {
    int rb = wm * 64 + m * 16 + quad * 4;
#pragma unroll
    for (int n = 0; n < 4; n++) {
      int col = wn * 64 + n * 16 + qm;
#pragma unroll
      for (int reg = 0; reg < 4; reg++)
        smem[(rb + reg) * 136 + col] = f2bf(acc[m][n][reg]);
    }
  }
  __syncthreads();
  { // each (row, half) copies its FULL 64-short half: 8 x uint4
    int row = tid >> 1, half = tid & 1;
    const uint4* src = (const uint4*)(smem + row * 136 + half * 64);
    uint4 v[8];
#pragma unroll
    for (int u = 0; u < 8; u++) v[u] = src[u];
    uint4* dst = (uint4*)(triT + (size_t)d * RTOT + (size_t)(i0 + row) * 512 + j0 + half * 64);
#pragma unroll
    for (int u = 0; u < 8; u++) dst[u] = v[u];
  }
}

// ---------------------------------------------------------------------------
// K3: LN2 over d=128 of tri (channel-major input), @ W_out^T + b_out, * gate.
// Latency fix (this round): ALL global reads issued in one prologue burst
// BEFORE the staging LDS writes (stage uint4s, B-frags, all-4-m masks, m=0
// gate A2, bias scalars); gate A2 loads software-pipelined (prefetch m+1 at
// top of iter m, static double-buffer).  m-loop has ZERO in-loop dependent
// global loads.  Everything else identical to round-4 passing version.
// ---------------------------------------------------------------------------
__global__ __launch_bounds__(256) void out_kernel(
    const unsigned short* __restrict__ triT, const unsigned short* __restrict__ Woutb,
    const float* __restrict__ ln2w, const float* __restrict__ ln2b,
    const float* __restrict__ b_out, float* __restrict__ out,
    const unsigned short* __restrict__ xb, const unsigned short* __restrict__ Wc,
    const float* __restrict__ bc, const int* __restrict__ mask, int fuse) {
  __shared__ unsigned short nt[64][136];
  __shared__ float mu_s[64], rs_s[64];
  int r0 = blockIdx.x * 64;
  int tid = threadIdx.x;
  int wv = tid >> 6, lane = tid & 63;
  int qm = lane & 15, quad = lane >> 4;

  // ---- prologue: issue every global read up front (max MLP) ----
  int dch = tid >> 1, half = tid & 1;
  const uint4* src = (const uint4*)(triT + (size_t)dch * RTOT + r0 + half * 32);
  uint4 sv0 = src[0], sv1 = src[1], sv2 = src[2], sv3 = src[3];

  // B fragments for this wave's 32 output cols.
  bf16x8 Bo[2][4], Bg[2][4];
#pragma unroll
  for (int ft = 0; ft < 2; ft++)
#pragma unroll
    for (int kk = 0; kk < 4; kk++) {
      int c = wv * 32 + ft * 16 + qm;
      int ko = kk * 32 + quad * 8;
      Bo[ft][kk] = *(const bf16x8*)(Woutb + (size_t)c * 128 + ko);
      if (fuse) Bg[ft][kk] = *(const bf16x8*)(Wc + (size_t)(512 + c) * 128 + ko);
    }

  // masks for all 4 m-steps; bias scalars.
  int4 mi4[4];
  float bo_[2], bG_[2];
#pragma unroll
  for (int ft = 0; ft < 2; ft++) {
    int c = wv * 32 + ft * 16 + qm;
    bo_[ft] = b_out[c];
    bG_[ft] = fuse ? bc[512 + c] : 0.f;
  }
  if (fuse) {
#pragma unroll
    for (int m = 0; m < 4; m++) mi4[m] = *(const int4*)(mask + r0 + m * 16 + quad * 4);
  }

  // gate A2: prefetch m=0 (double-buffered across the m-loop).
  const unsigned short* xA = xb + (size_t)(r0 + qm) * 128 + quad * 8;
  bf16x8 a2cur[4], a2nxt[4];
  if (fuse) {
#pragma unroll
    for (int kk = 0; kk < 4; kk++) a2cur[kk] = *(const bf16x8*)(xA + kk * 32);
  }

  { // LDS staging writes (vmcnt waits only on the sv0..3 loads)
    uint4 v[4] = {sv0, sv1, sv2, sv3};
    const unsigned short* pv = (const unsigned short*)v;
#pragma unroll
    for (int u = 0; u < 32; u++) nt[half * 32 + u][dch] = pv[u];
  }
  __syncthreads();

  { // LN2 stats: 4 lanes per position (round-2 verbatim)
    int p = tid >> 2, part = tid & 3;
    float s = 0.f, sq = 0.f;
#pragma unroll
    for (int u = 0; u < 4; u++) {
      bf16x8 v = *(const bf16x8*)(&nt[p][part * 32 + u * 8]);
#pragma unroll
      for (int e = 0; e < 8; e++) {
        float f = bf2f((unsigned short)v[e]);
        s += f; sq += f * f;
      }
    }
    s += __shfl_xor(s, 1); sq += __shfl_xor(sq, 1);
    s += __shfl_xor(s, 2); sq += __shfl_xor(sq, 2);
    float mu = s * (1.f / 128.f);
    float var = sq * (1.f / 128.f) - mu * mu;
    if (part == 0) { mu_s[p] = mu; rs_s[p] = rsqrtf(var + 1e-5f); }
  }
  __syncthreads();

#pragma unroll
  for (int m = 0; m < 4; m++) { // 4 row-steps of 16 rows
    // prefetch next m's gate A2 first: latency hides under afr VALU + MFMA
    if (fuse && m < 3) {
#pragma unroll
      for (int kk = 0; kk < 4; kk++)
        a2nxt[kk] = *(const bf16x8*)(xA + (m + 1) * 2048 + kk * 32);
    }

    int rl = m * 16 + qm;
    float mu = mu_s[rl], rs = rs_s[rl];

    // Build normalized A-fragments in registers (round-2 arithmetic).
    bf16x8 afr[4];
#pragma unroll
    for (int kk = 0; kk < 4; kk++) {
      int ko = kk * 32 + quad * 8;
      bf16x8 raw = *(const bf16x8*)(&nt[rl][ko]);
#pragma unroll
      for (int e = 0; e < 8; e++) {
        float wf = ln2w[ko + e], bv = ln2b[ko + e];
        afr[kk][e] = (short)f2bf((bf2f((unsigned short)raw[e]) - mu) * rs * wf + bv);
      }
    }

    f32x4 accO[2], accG[2];
#pragma unroll
    for (int ft = 0; ft < 2; ft++) {
      accO[ft] = (f32x4){0.f, 0.f, 0.f, 0.f};
      accG[ft] = (f32x4){0.f, 0.f, 0.f, 0.f};
    }
#pragma unroll
    for (int kk = 0; kk < 4; kk++) {
#pragma unroll
      for (int ft = 0; ft < 2; ft++)
        accO[ft] = __builtin_amdgcn_mfma_f32_16x16x32_bf16(afr[kk], Bo[ft][kk], accO[ft], 0, 0, 0);
      if (fuse) {
#pragma unroll
        for (int ft = 0; ft < 2; ft++)
          accG[ft] = __builtin_amdgcn_mfma_f32_16x16x32_bf16(a2cur[kk], Bg[ft][kk], accG[ft], 0, 0, 0);
      }
    }

    int rbase = r0 + m * 16 + quad * 4;
    if (fuse) {
      int4 mi = mi4[m];
      float mk[4] = {mi.x ? 1.f : 0.f, mi.y ? 1.f : 0.f, mi.z ? 1.f : 0.f, mi.w ? 1.f : 0.f};
#pragma unroll
      for (int ft = 0; ft < 2; ft++) {
        int c = wv * 32 + ft * 16 + qm;
#pragma unroll
        for (int reg = 0; reg < 4; reg++) {
          float g = sigmoidf(accG[ft][reg] + bG_[ft]) * mk[reg];
          out[(size_t)(rbase + reg) * 128 + c] = (accO[ft][reg] + bo_[ft]) * g;
        }
      }
      // rotate double-buffer (register moves, static after unroll)
#pragma unroll
      for (int kk = 0; kk < 4; kk++) a2cur[kk] = a2nxt[kk];
    } else {
#pragma unroll
      for (int ft = 0; ft < 2; ft++) {
        int c = wv * 32 + ft * 16 + qm;
#pragma unroll
        for (int reg = 0; reg < 4; reg++) {
          size_t off = (size_t)(rbase + reg) * 128 + c;
          out[off] = (accO[ft][reg] + bo_[ft]) * out[off]; // out[] holds gate
        }
      }
    }
  }
}

// ---------------------------------------------------------------------------
extern "C" void kernel_launch(void* const* d_in, const int* in_sizes, int n_in,
                              void* d_out, int out_size, void* d_ws, size_t ws_size,
                              hipStream_t stream) {
  const float* edges = (const float*)d_in[0];
  const int* mask = (const int*)d_in[1];
  const float* ln1w = (const float*)d_in[2];
  const float* ln1b = (const float*)d_in[3];
  const float* W_fg = (const float*)d_in[4];
  const float* b_fg = (const float*)d_in[5];
  const float* W_go = (const float*)d_in[6];
  const float* b_go = (const float*)d_in[7];
  const float* ln2w = (const float*)d_in[8];
  const float* ln2b = (const float*)d_in[9];
  const float* W_out = (const float*)d_in[10];
  const float* b_out = (const float*)d_in[11];

  char* ws = (char*)d_ws;
  const size_t SZ = (size_t)RTOT * DCH * 2; // 64 MiB per bf16 buffer
  const size_t WSMALL = 0x40000;            // 256 KiB: Wc(160K)+bc(2.5K)+Woutb(32K), padded
  unsigned short* xb = (unsigned short*)ws;
  unsigned short* toT = (unsigned short*)(ws + SZ);
  unsigned short* fromT = (unsigned short*)(ws + 2 * SZ);
  unsigned short* Wc = (unsigned short*)(ws + 3 * SZ);
  float* bc = (float*)(ws + 3 * SZ + 640 * 128 * 2);
  unsigned short* Woutb = (unsigned short*)(ws + 3 * SZ + 640 * 128 * 2 + 640 * 4);
  float* gate = (float*)d_out;

  // If workspace allows, give triT its own buffer so xb survives -> fuse the
  // gate GEMM into out_kernel (kills 256 MiB of fp32 gate traffic + 1 launch).
  bool fits = ws_size >= 4 * SZ + WSMALL;
  unsigned short* triT = fits ? (unsigned short*)(ws + 3 * SZ + WSMALL) : xb;

  prep_kernel<<<384, 256, 0, stream>>>(W_fg, b_fg, W_go, b_go, W_out, Wc, bc, Woutb);
  ln1_kernel<<<RTOT / 4, 256, 0, stream>>>(edges, ln1w, ln1b, xb);
  fg_gemm_kernel<<<dim3(RTOT / 64, 2), 256, 0, stream>>>(xb, Wc, bc, mask, toT, fromT);
  if (!fits) go_gemm_kernel<<<RTOT / 64, 256, 0, stream>>>(xb, Wc, bc, mask, gate);
  tri_gemm_kernel<<<dim3(4, 4, 128), 256, 0, stream>>>(toT, fromT, triT);
  out_kernel<<<RTOT / 64, 256, 0, stream>>>(triT, Woutb, ln2w, ln2b, b_out,
                                            (float*)d_out, xb, Wc, bc, mask, fits ? 1 : 0);
}

// Round 6
// 565.560 us; speedup vs baseline: 1.3376x; 1.0528x over previous
//
#include <hip/hip_runtime.h>

#define NSEQ 512
#define DCH 128
#define RTOT (NSEQ * NSEQ) /* 262144 */

typedef __attribute__((ext_vector_type(8))) short bf16x8;
typedef __attribute__((ext_vector_type(4))) float f32x4;

__device__ __forceinline__ unsigned short f2bf(float v) {
  union { float f; unsigned int u; } x; x.f = v;
  unsigned int u = x.u;
  return (unsigned short)((u + 0x7fffu + ((u >> 16) & 1u)) >> 16);
}
__device__ __forceinline__ float bf2f(unsigned short s) {
  union { unsigned int u; float f; } x; x.u = ((unsigned int)s) << 16;
  return x.f;
}
__device__ __forceinline__ float sigmoidf(float x) { return 1.f / (1.f + __expf(-x)); }

// async global->LDS, 16B per lane; LDS dst is wave-uniform base (+ lane*16 implicit)
__device__ __forceinline__ void async16(const unsigned short* g, unsigned short* l) {
  __builtin_amdgcn_global_load_lds(
      (const __attribute__((address_space(1))) unsigned int*)g,
      (__attribute__((address_space(3))) unsigned int*)l, 16, 0, 0);
}

// ---------------------------------------------------------------------------
// prep: pack weights (reordered) into bf16.  Wc rows: [0,128)=to-feat,
// [128,256)=to-gate, [256,384)=from-feat, [384,512)=from-gate, [512,640)=go.
// ---------------------------------------------------------------------------
__global__ void prep_kernel(const float* __restrict__ W_fg, const float* __restrict__ b_fg,
                            const float* __restrict__ W_go, const float* __restrict__ b_go,
                            const float* __restrict__ W_out,
                            unsigned short* __restrict__ Wc, float* __restrict__ bc,
                            unsigned short* __restrict__ Woutb) {
  int idx = blockIdx.x * 256 + threadIdx.x;
  if (idx < 640 * 128) {
    int rr = idx >> 7, k = idx & 127;
    float v, bv;
    if (rr < 512) {
      int m = rr >> 7;
      int srow = (m == 1) ? rr + 128 : (m == 2) ? rr - 128 : rr;
      v = W_fg[srow * 128 + k];
      bv = b_fg[srow];
    } else {
      int srow = rr - 512;
      v = W_go[srow * 128 + k];
      bv = b_go[srow];
    }
    Wc[idx] = f2bf(v);
    if (k == 0) bc[rr] = bv;
  } else {
    int i2 = idx - 640 * 128;
    if (i2 < 128 * 128) Woutb[i2] = f2bf(W_out[i2]);
  }
}

// ---------------------------------------------------------------------------
// K0: LayerNorm over last dim (128) of edges; write x as bf16. 1 wave = 1 row.
// ---------------------------------------------------------------------------
__global__ __launch_bounds__(256) void ln1_kernel(const float* __restrict__ edges,
                                                  const float* __restrict__ w,
                                                  const float* __restrict__ b,
                                                  unsigned short* __restrict__ xb) {
  int wv = threadIdx.x >> 6;
  int lane = threadIdx.x & 63;
  size_t row = (size_t)blockIdx.x * 4 + wv;
  const float2* e = (const float2*)(edges + row * 128);
  float2 v = e[lane];
  float s = v.x + v.y, sq = v.x * v.x + v.y * v.y;
#pragma unroll
  for (int off = 32; off; off >>= 1) {
    s += __shfl_xor(s, off);
    sq += __shfl_xor(sq, off);
  }
  float mu = s * (1.f / 128.f);
  float var = sq * (1.f / 128.f) - mu * mu;
  float rs = rsqrtf(var + 1e-5f);
  int c = lane * 2;
  float x0 = (v.x - mu) * rs * w[c] + b[c];
  float x1 = (v.y - mu) * rs * w[c + 1] + b[c + 1];
  unsigned int packed = (unsigned int)f2bf(x0) | ((unsigned int)f2bf(x1) << 16);
  ((unsigned int*)(xb + row * 128))[lane] = packed;
}

// ---------------------------------------------------------------------------
// K1a: fg GEMM + gating + mask.  Col-split waves, B fragments hoisted into
// registers (Wc block-invariant).  LDS transpose epilogue -> 128B-line stores.
// ---------------------------------------------------------------------------
__global__ __launch_bounds__(256) void fg_gemm_kernel(
    const unsigned short* __restrict__ xb, const unsigned short* __restrict__ Wc,
    const float* __restrict__ bc, const int* __restrict__ mask,
    unsigned short* __restrict__ toT, unsigned short* __restrict__ fromT) {
  __shared__ unsigned int Cs[128 * 36]; // 128 planes x 64 rows bf16 (pad 36 uints/plane)
  int nb = blockIdx.y;
  int wv = threadIdx.x >> 6, lane = threadIdx.x & 63;
  int qm = lane & 15, quad = lane >> 4;
  int r0 = blockIdx.x * 64;
  int nbase = nb * 256;

  // Hoisted B fragments: feat cols nbase+wv*32+ft*16, gate cols +128.
  bf16x8 Bf[2][4], Bg[2][4];
#pragma unroll
  for (int ft = 0; ft < 2; ft++)
#pragma unroll
    for (int kk = 0; kk < 4; kk++) {
      int ko = kk * 32 + quad * 8;
      Bf[ft][kk] = *(const bf16x8*)(Wc + (size_t)(nbase + wv * 32 + ft * 16 + qm) * 128 + ko);
      Bg[ft][kk] = *(const bf16x8*)(Wc + (size_t)(nbase + 128 + wv * 32 + ft * 16 + qm) * 128 + ko);
    }

#pragma unroll
  for (int m = 0; m < 4; m++) { // 4 row-steps of 16 rows
    int rw = r0 + m * 16;
    f32x4 accf[2], accg[2];
#pragma unroll
    for (int ft = 0; ft < 2; ft++) {
      accf[ft] = (f32x4){0.f, 0.f, 0.f, 0.f};
      accg[ft] = (f32x4){0.f, 0.f, 0.f, 0.f};
    }
#pragma unroll
    for (int kk = 0; kk < 4; kk++) {
      int ko = kk * 32 + quad * 8;
      bf16x8 a = *(const bf16x8*)(xb + (size_t)(rw + qm) * 128 + ko);
#pragma unroll
      for (int ft = 0; ft < 2; ft++) {
        accf[ft] = __builtin_amdgcn_mfma_f32_16x16x32_bf16(a, Bf[ft][kk], accf[ft], 0, 0, 0);
        accg[ft] = __builtin_amdgcn_mfma_f32_16x16x32_bf16(a, Bg[ft][kk], accg[ft], 0, 0, 0);
      }
    }
    int rbase = rw + quad * 4;
    int4 mi = *(const int4*)(mask + rbase);
    float mk[4] = {mi.x ? 1.f : 0.f, mi.y ? 1.f : 0.f, mi.z ? 1.f : 0.f, mi.w ? 1.f : 0.f};
#pragma unroll
    for (int ft = 0; ft < 2; ft++) {
      int c = wv * 32 + ft * 16 + qm; // local col 0..127
      float bF = bc[nbase + c];
      float bG = bc[nbase + 128 + c];
      float v0 = (accf[ft][0] + bF) * sigmoidf(accg[ft][0] + bG) * mk[0];
      float v1 = (accf[ft][1] + bF) * sigmoidf(accg[ft][1] + bG) * mk[1];
      float v2 = (accf[ft][2] + bF) * sigmoidf(accg[ft][2] + bG) * mk[2];
      float v3 = (accf[ft][3] + bF) * sigmoidf(accg[ft][3] + bG) * mk[3];
      unsigned int u0 = (unsigned int)f2bf(v0) | ((unsigned int)f2bf(v1) << 16);
      unsigned int u1 = (unsigned int)f2bf(v2) | ((unsigned int)f2bf(v3) << 16);
      *(uint2*)(Cs + c * 36 + m * 8 + quad * 2) = (uint2){u0, u1};
    }
  }
  __syncthreads();
  { // wave writes its own 32 planes; 8 lanes/plane -> 128B contiguous lines
    unsigned short* dst = (nb == 0) ? toT : fromT;
    int pl = lane >> 3, lo = lane & 7;
#pragma unroll
    for (int i = 0; i < 4; i++) {
      int p = wv * 32 + i * 8 + pl;
      uint4 v = *(const uint4*)(Cs + p * 36 + lo * 4);
      *(uint4*)(dst + (size_t)p * RTOT + r0 + lo * 8) = v;
    }
  }
}

// ---------------------------------------------------------------------------
// K1b (FALLBACK ONLY, used when workspace too small to de-alias triT):
// out_gate = sigmoid(x @ W_go^T + b_go) * mask, fp32, into d_out.
// ---------------------------------------------------------------------------
__global__ __launch_bounds__(256) void go_gemm_kernel(
    const unsigned short* __restrict__ xb, const unsigned short* __restrict__ Wc,
    const float* __restrict__ bc, const int* __restrict__ mask,
    float* __restrict__ gate_out) {
  int wv = threadIdx.x >> 6, lane = threadIdx.x & 63;
  int qm = lane & 15, quad = lane >> 4;
  int rw = blockIdx.x * 64 + wv * 16;

  f32x4 acc[8];
#pragma unroll
  for (int t = 0; t < 8; t++) acc[t] = (f32x4){0.f, 0.f, 0.f, 0.f};

#pragma unroll
  for (int kk = 0; kk < 4; kk++) {
    int ko = kk * 32 + quad * 8;
    bf16x8 a = *(const bf16x8*)(xb + (size_t)(rw + qm) * 128 + ko);
#pragma unroll
    for (int t = 0; t < 8; t++) {
      bf16x8 bf = *(const bf16x8*)(Wc + (size_t)(512 + t * 16 + qm) * 128 + ko);
      acc[t] = __builtin_amdgcn_mfma_f32_16x16x32_bf16(a, bf, acc[t], 0, 0, 0);
    }
  }

  int rbase = rw + quad * 4;
  int4 mi = *(const int4*)(mask + rbase);
  float mk[4] = {mi.x ? 1.f : 0.f, mi.y ? 1.f : 0.f, mi.z ? 1.f : 0.f, mi.w ? 1.f : 0.f};
#pragma unroll
  for (int t = 0; t < 8; t++) {
    int c = t * 16 + qm;
    float bG = bc[512 + c];
#pragma unroll
    for (int reg = 0; reg < 4; reg++) {
      float g = sigmoidf(acc[t][reg] + bG) * mk[reg];
      gate_out[(size_t)(rbase + reg) * 128 + c] = g;
    }
  }
}

// ---------------------------------------------------------------------------
// K2: tri[d] = To_d (512x512) @ From_d^T, 128 batched NT GEMMs.
// 128x128 tile/block, BK=64, global_load_lds(16B) staging, 4 waves x (4x4)
// MFMA accs.  XCD d-clustered swizzle: linear wgid round-robins XCDs (n%8),
// so map XCD k -> d in [16k,16k+16): the 16 blocks sharing a d-plane's A/B
// panels co-reside on ONE XCD's L2 instead of interleaving all 128 d's.
// ---------------------------------------------------------------------------
__global__ __launch_bounds__(256) void tri_gemm_kernel(
    const unsigned short* __restrict__ toT, const unsigned short* __restrict__ fromT,
    unsigned short* __restrict__ triT) {
  __shared__ unsigned short smem[128 * 136]; // K-loop: As=[0,8192) Bs=[8192,16384); epilogue: C 128x136
  unsigned short* As = smem;
  unsigned short* Bs = smem + 128 * 64;

  // bijective remap of (x,y,z) -> (i0,j0,d), d-clustered per XCD
  int n = (int)(blockIdx.x + (blockIdx.y << 2) + (blockIdx.z << 4)); // 0..2047
  int xcd = n & 7, s = n >> 3;                                        // s: 0..255
  int d = xcd * 16 + (s >> 4);
  int xy = s & 15;
  int i0 = (xy & 3) * 128, j0 = (xy >> 2) * 128;

  int tid = threadIdx.x, w = tid >> 6, lane = tid & 63;
  int qm = lane & 15, quad = lane >> 4;
  int wm = w >> 1, wn = w & 1;
  const unsigned short* A = toT + (size_t)d * RTOT;
  const unsigned short* B = fromT + (size_t)d * RTOT;
  int lr = lane >> 3, lk = (lane & 7) * 8;

  f32x4 acc[4][4];
#pragma unroll
  for (int m = 0; m < 4; m++)
#pragma unroll
    for (int n2 = 0; n2 < 4; n2++) acc[m][n2] = (f32x4){0.f, 0.f, 0.f, 0.f};

  for (int kb = 0; kb < 512; kb += 64) {
    __syncthreads(); // prev compute done reading LDS
#pragma unroll
    for (int q = 0; q < 4; q++) {
      int blk = w * 4 + q; // 16 row-blocks of 8 rows each
      async16(A + (size_t)(i0 + blk * 8 + lr) * 512 + kb + lk, As + blk * 512);
      async16(B + (size_t)(j0 + blk * 8 + lr) * 512 + kb + lk, Bs + blk * 512);
    }
    __syncthreads(); // loads drained (compiler emits vmcnt(0) before barrier)
#pragma unroll
    for (int kk = 0; kk < 2; kk++) {
      bf16x8 af[4], bfr[4];
#pragma unroll
      for (int m = 0; m < 4; m++)
        af[m] = *(const bf16x8*)(As + (wm * 64 + m * 16 + qm) * 64 + kk * 32 + quad * 8);
#pragma unroll
      for (int n2 = 0; n2 < 4; n2++)
        bfr[n2] = *(const bf16x8*)(Bs + (wn * 64 + n2 * 16 + qm) * 64 + kk * 32 + quad * 8);
#pragma unroll
      for (int m = 0; m < 4; m++)
#pragma unroll
        for (int n2 = 0; n2 < 4; n2++)
          acc[m][n2] = __builtin_amdgcn_mfma_f32_16x16x32_bf16(af[m], bfr[n2], acc[m][n2], 0, 0, 0);
    }
  }

  __syncthreads(); // done with As/Bs; reuse smem as C 128x136 (pad keeps 16B align, kills conflicts)
#pragma unroll
  for (int m = 0; m < 4; m++) {
    int rb = wm * 64 + m * 16 + quad * 4;
#pragma unroll
    for (int n2 = 0; n2 < 4; n2++) {
      int col = wn * 64 + n2 * 16 + qm;
#pragma unroll
      for (int reg = 0; reg < 4; reg++)
        smem[(rb + reg) * 136 + col] = f2bf(acc[m][n2][reg]);
    }
  }
  __syncthreads();
  { // each (row, half) copies its FULL 64-short half: 8 x uint4
    int row = tid >> 1, half = tid & 1;
    const uint4* src = (const uint4*)(smem + row * 136 + half * 64);
    uint4 v[8];
#pragma unroll
    for (int u = 0; u < 8; u++) v[u] = src[u];
    uint4* dst = (uint4*)(triT + (size_t)d * RTOT + (size_t)(i0 + row) * 512 + j0 + half * 64);
#pragma unroll
    for (int u = 0; u < 8; u++) dst[u] = v[u];
  }
}

// ---------------------------------------------------------------------------
// K3: LN2 over d=128 of tri (channel-major input), @ W_out^T + b_out, * gate.
// 128-row blocks this round: channel-major read chunks double to 256B, half
// the blocks, 8 m-steps amortize prologue/barriers.  All global reads still
// issued in one prologue burst; gate A2 software-pipelined across m.
// ---------------------------------------------------------------------------
__global__ __launch_bounds__(256) void out_kernel(
    const unsigned short* __restrict__ triT, const unsigned short* __restrict__ Woutb,
    const float* __restrict__ ln2w, const float* __restrict__ ln2b,
    const float* __restrict__ b_out, float* __restrict__ out,
    const unsigned short* __restrict__ xb, const unsigned short* __restrict__ Wc,
    const float* __restrict__ bc, const int* __restrict__ mask, int fuse) {
  __shared__ unsigned short nt[128][136];
  __shared__ float mu_s[128], rs_s[128];
  int r0 = blockIdx.x * 128;
  int tid = threadIdx.x;
  int wv = tid >> 6, lane = tid & 63;
  int qm = lane & 15, quad = lane >> 4;

  // ---- prologue: issue every global read up front (max MLP) ----
  int dch = tid >> 1, half = tid & 1; // dch: 0..127 channel, half: 64 positions each
  const uint4* src = (const uint4*)(triT + (size_t)dch * RTOT + r0 + half * 64);
  uint4 sv[8];
#pragma unroll
  for (int u = 0; u < 8; u++) sv[u] = src[u];

  // B fragments for this wave's 32 output cols.
  bf16x8 Bo[2][4], Bg[2][4];
#pragma unroll
  for (int ft = 0; ft < 2; ft++)
#pragma unroll
    for (int kk = 0; kk < 4; kk++) {
      int c = wv * 32 + ft * 16 + qm;
      int ko = kk * 32 + quad * 8;
      Bo[ft][kk] = *(const bf16x8*)(Woutb + (size_t)c * 128 + ko);
      if (fuse) Bg[ft][kk] = *(const bf16x8*)(Wc + (size_t)(512 + c) * 128 + ko);
    }

  // masks for all 8 m-steps; bias scalars.
  int4 mi4[8];
  float bo_[2], bG_[2];
#pragma unroll
  for (int ft = 0; ft < 2; ft++) {
    int c = wv * 32 + ft * 16 + qm;
    bo_[ft] = b_out[c];
    bG_[ft] = fuse ? bc[512 + c] : 0.f;
  }
  if (fuse) {
#pragma unroll
    for (int m = 0; m < 8; m++) mi4[m] = *(const int4*)(mask + r0 + m * 16 + quad * 4);
  }

  // gate A2: prefetch m=0 (double-buffered across the m-loop).
  const unsigned short* xA = xb + (size_t)(r0 + qm) * 128 + quad * 8;
  bf16x8 a2cur[4], a2nxt[4];
  if (fuse) {
#pragma unroll
    for (int kk = 0; kk < 4; kk++) a2cur[kk] = *(const bf16x8*)(xA + kk * 32);
  }

  { // LDS staging writes (vmcnt waits only on the sv loads)
    const unsigned short* pv = (const unsigned short*)sv;
#pragma unroll
    for (int u = 0; u < 64; u++) nt[half * 64 + u][dch] = pv[u];
  }
  __syncthreads();

  { // LN2 stats: 2 lanes per position (each sums 64 channels)
    int p = tid >> 1, part = tid & 1;
    float s = 0.f, sq = 0.f;
#pragma unroll
    for (int u = 0; u < 8; u++) {
      bf16x8 v = *(const bf16x8*)(&nt[p][part * 64 + u * 8]);
#pragma unroll
      for (int e = 0; e < 8; e++) {
        float f = bf2f((unsigned short)v[e]);
        s += f; sq += f * f;
      }
    }
    s += __shfl_xor(s, 1); sq += __shfl_xor(sq, 1);
    float mu = s * (1.f / 128.f);
    float var = sq * (1.f / 128.f) - mu * mu;
    if (part == 0) { mu_s[p] = mu; rs_s[p] = rsqrtf(var + 1e-5f); }
  }
  __syncthreads();

#pragma unroll
  for (int m = 0; m < 8; m++) { // 8 row-steps of 16 rows
    // prefetch next m's gate A2 first: latency hides under afr VALU + MFMA
    if (fuse && m < 7) {
#pragma unroll
      for (int kk = 0; kk < 4; kk++)
        a2nxt[kk] = *(const bf16x8*)(xA + (m + 1) * 2048 + kk * 32);
    }

    int rl = m * 16 + qm;
    float mu = mu_s[rl], rs = rs_s[rl];

    // Build normalized A-fragments in registers.
    bf16x8 afr[4];
#pragma unroll
    for (int kk = 0; kk < 4; kk++) {
      int ko = kk * 32 + quad * 8;
      bf16x8 raw = *(const bf16x8*)(&nt[rl][ko]);
#pragma unroll
      for (int e = 0; e < 8; e++) {
        float wf = ln2w[ko + e], bv = ln2b[ko + e];
        afr[kk][e] = (short)f2bf((bf2f((unsigned short)raw[e]) - mu) * rs * wf + bv);
      }
    }

    f32x4 accO[2], accG[2];
#pragma unroll
    for (int ft = 0; ft < 2; ft++) {
      accO[ft] = (f32x4){0.f, 0.f, 0.f, 0.f};
      accG[ft] = (f32x4){0.f, 0.f, 0.f, 0.f};
    }
#pragma unroll
    for (int kk = 0; kk < 4; kk++) {
#pragma unroll
      for (int ft = 0; ft < 2; ft++)
        accO[ft] = __builtin_amdgcn_mfma_f32_16x16x32_bf16(afr[kk], Bo[ft][kk], accO[ft], 0, 0, 0);
      if (fuse) {
#pragma unroll
        for (int ft = 0; ft < 2; ft++)
          accG[ft] = __builtin_amdgcn_mfma_f32_16x16x32_bf16(a2cur[kk], Bg[ft][kk], accG[ft], 0, 0, 0);
      }
    }

    int rbase = r0 + m * 16 + quad * 4;
    if (fuse) {
      int4 mi = mi4[m];
      float mk[4] = {mi.x ? 1.f : 0.f, mi.y ? 1.f : 0.f, mi.z ? 1.f : 0.f, mi.w ? 1.f : 0.f};
#pragma unroll
      for (int ft = 0; ft < 2; ft++) {
        int c = wv * 32 + ft * 16 + qm;
#pragma unroll
        for (int reg = 0; reg < 4; reg++) {
          float g = sigmoidf(accG[ft][reg] + bG_[ft]) * mk[reg];
          out[(size_t)(rbase + reg) * 128 + c] = (accO[ft][reg] + bo_[ft]) * g;
        }
      }
      // rotate double-buffer (register moves, static after unroll)
#pragma unroll
      for (int kk = 0; kk < 4; kk++) a2cur[kk] = a2nxt[kk];
    } else {
#pragma unroll
      for (int ft = 0; ft < 2; ft++) {
        int c = wv * 32 + ft * 16 + qm;
#pragma unroll
        for (int reg = 0; reg < 4; reg++) {
          size_t off = (size_t)(rbase + reg) * 128 + c;
          out[off] = (accO[ft][reg] + bo_[ft]) * out[off]; // out[] holds gate
        }
      }
    }
  }
}

// ---------------------------------------------------------------------------
extern "C" void kernel_launch(void* const* d_in, const int* in_sizes, int n_in,
                              void* d_out, int out_size, void* d_ws, size_t ws_size,
                              hipStream_t stream) {
  const float* edges = (const float*)d_in[0];
  const int* mask = (const int*)d_in[1];
  const float* ln1w = (const float*)d_in[2];
  const float* ln1b = (const float*)d_in[3];
  const float* W_fg = (const float*)d_in[4];
  const float* b_fg = (const float*)d_in[5];
  const float* W_go = (const float*)d_in[6];
  const float* b_go = (const float*)d_in[7];
  const float* ln2w = (const float*)d_in[8];
  const float* ln2b = (const float*)d_in[9];
  const float* W_out = (const float*)d_in[10];
  const float* b_out = (const float*)d_in[11];

  char* ws = (char*)d_ws;
  const size_t SZ = (size_t)RTOT * DCH * 2; // 64 MiB per bf16 buffer
  const size_t WSMALL = 0x40000;            // 256 KiB: Wc(160K)+bc(2.5K)+Woutb(32K), padded
  unsigned short* xb = (unsigned short*)ws;
  unsigned short* toT = (unsigned short*)(ws + SZ);
  unsigned short* fromT = (unsigned short*)(ws + 2 * SZ);
  unsigned short* Wc = (unsigned short*)(ws + 3 * SZ);
  float* bc = (float*)(ws + 3 * SZ + 640 * 128 * 2);
  unsigned short* Woutb = (unsigned short*)(ws + 3 * SZ + 640 * 128 * 2 + 640 * 4);
  float* gate = (float*)d_out;

  // If workspace allows, give triT its own buffer so xb survives -> fuse the
  // gate GEMM into out_kernel (kills 256 MiB of fp32 gate traffic + 1 launch).
  bool fits = ws_size >= 4 * SZ + WSMALL;
  unsigned short* triT = fits ? (unsigned short*)(ws + 3 * SZ + WSMALL) : xb;

  prep_kernel<<<384, 256, 0, stream>>>(W_fg, b_fg, W_go, b_go, W_out, Wc, bc, Woutb);
  ln1_kernel<<<RTOT / 4, 256, 0, stream>>>(edges, ln1w, ln1b, xb);
  fg_gemm_kernel<<<dim3(RTOT / 64, 2), 256, 0, stream>>>(xb, Wc, bc, mask, toT, fromT);
  if (!fits) go_gemm_kernel<<<RTOT / 64, 256, 0, stream>>>(xb, Wc, bc, mask, gate);
  tri_gemm_kernel<<<dim3(4, 4, 128), 256, 0, stream>>>(toT, fromT, triT);
  out_kernel<<<RTOT / 128, 256, 0, stream>>>(triT, Woutb, ln2w, ln2b, b_out,
                                             (float*)d_out, xb, Wc, bc, mask, fits ? 1 : 0);
}

// Round 7
// 561.122 us; speedup vs baseline: 1.3481x; 1.0079x over previous
//
#include <hip/hip_runtime.h>

#define NSEQ 512
#define DCH 128
#define RTOT (NSEQ * NSEQ) /* 262144 */

typedef __attribute__((ext_vector_type(8))) short bf16x8;
typedef __attribute__((ext_vector_type(4))) float f32x4;

__device__ __forceinline__ unsigned short f2bf(float v) {
  union { float f; unsigned int u; } x; x.f = v;
  unsigned int u = x.u;
  return (unsigned short)((u + 0x7fffu + ((u >> 16) & 1u)) >> 16);
}
__device__ __forceinline__ float bf2f(unsigned short s) {
  union { unsigned int u; float f; } x; x.u = ((unsigned int)s) << 16;
  return x.f;
}
__device__ __forceinline__ float sigmoidf(float x) { return 1.f / (1.f + __expf(-x)); }

// async global->LDS, 16B per lane; LDS dst is wave-uniform base (+ lane*16 implicit)
__device__ __forceinline__ void async16(const unsigned short* g, unsigned short* l) {
  __builtin_amdgcn_global_load_lds(
      (const __attribute__((address_space(1))) unsigned int*)g,
      (__attribute__((address_space(3))) unsigned int*)l, 16, 0, 0);
}

// ---------------------------------------------------------------------------
// prep: pack weights (reordered) into bf16.  Wc rows: [0,128)=to-feat,
// [128,256)=to-gate, [256,384)=from-feat, [384,512)=from-gate, [512,640)=go.
// ---------------------------------------------------------------------------
__global__ void prep_kernel(const float* __restrict__ W_fg, const float* __restrict__ b_fg,
                            const float* __restrict__ W_go, const float* __restrict__ b_go,
                            const float* __restrict__ W_out,
                            unsigned short* __restrict__ Wc, float* __restrict__ bc,
                            unsigned short* __restrict__ Woutb) {
  int idx = blockIdx.x * 256 + threadIdx.x;
  if (idx < 640 * 128) {
    int rr = idx >> 7, k = idx & 127;
    float v, bv;
    if (rr < 512) {
      int m = rr >> 7;
      int srow = (m == 1) ? rr + 128 : (m == 2) ? rr - 128 : rr;
      v = W_fg[srow * 128 + k];
      bv = b_fg[srow];
    } else {
      int srow = rr - 512;
      v = W_go[srow * 128 + k];
      bv = b_go[srow];
    }
    Wc[idx] = f2bf(v);
    if (k == 0) bc[rr] = bv;
  } else {
    int i2 = idx - 640 * 128;
    if (i2 < 128 * 128) Woutb[i2] = f2bf(W_out[i2]);
  }
}

// ---------------------------------------------------------------------------
// K0: LayerNorm over last dim (128) of edges; write x as bf16. 1 wave = 1 row.
// ---------------------------------------------------------------------------
__global__ __launch_bounds__(256) void ln1_kernel(const float* __restrict__ edges,
                                                  const float* __restrict__ w,
                                                  const float* __restrict__ b,
                                                  unsigned short* __restrict__ xb) {
  int wv = threadIdx.x >> 6;
  int lane = threadIdx.x & 63;
  size_t row = (size_t)blockIdx.x * 4 + wv;
  const float2* e = (const float2*)(edges + row * 128);
  float2 v = e[lane];
  float s = v.x + v.y, sq = v.x * v.x + v.y * v.y;
#pragma unroll
  for (int off = 32; off; off >>= 1) {
    s += __shfl_xor(s, off);
    sq += __shfl_xor(sq, off);
  }
  float mu = s * (1.f / 128.f);
  float var = sq * (1.f / 128.f) - mu * mu;
  float rs = rsqrtf(var + 1e-5f);
  int c = lane * 2;
  float x0 = (v.x - mu) * rs * w[c] + b[c];
  float x1 = (v.y - mu) * rs * w[c + 1] + b[c + 1];
  unsigned int packed = (unsigned int)f2bf(x0) | ((unsigned int)f2bf(x1) << 16);
  ((unsigned int*)(xb + row * 128))[lane] = packed;
}

// ---------------------------------------------------------------------------
// K1a: fg GEMM + gating + mask.  Col-split waves.  THIS ROUND: full prologue
// burst — all 16 A-fragments (4m x 4kk), 16 B-fragments, masks, biases loaded
// to registers up front (32x16B loads in flight; VGPR ~160).  The old form
// (VGPR 88) left the allocator no headroom, so A-loads serialized against L3
// latency (~20K cyc/wave, occupancy 21%).  m-loop is now pure compute.
// ---------------------------------------------------------------------------
__global__ __launch_bounds__(256) void fg_gemm_kernel(
    const unsigned short* __restrict__ xb, const unsigned short* __restrict__ Wc,
    const float* __restrict__ bc, const int* __restrict__ mask,
    unsigned short* __restrict__ toT, unsigned short* __restrict__ fromT) {
  __shared__ unsigned int Cs[128 * 36]; // 128 planes x 64 rows bf16 (pad 36 uints/plane)
  int nb = blockIdx.y;
  int wv = threadIdx.x >> 6, lane = threadIdx.x & 63;
  int qm = lane & 15, quad = lane >> 4;
  int r0 = blockIdx.x * 64;
  int nbase = nb * 256;

  // ---- prologue: every global read issued up front ----
  bf16x8 Areg[4][4]; // [m][kk] — static indexing only (full unroll)
#pragma unroll
  for (int m = 0; m < 4; m++)
#pragma unroll
    for (int kk = 0; kk < 4; kk++)
      Areg[m][kk] = *(const bf16x8*)(xb + (size_t)(r0 + m * 16 + qm) * 128 + kk * 32 + quad * 8);

  bf16x8 Bf[2][4], Bg[2][4];
#pragma unroll
  for (int ft = 0; ft < 2; ft++)
#pragma unroll
    for (int kk = 0; kk < 4; kk++) {
      int ko = kk * 32 + quad * 8;
      Bf[ft][kk] = *(const bf16x8*)(Wc + (size_t)(nbase + wv * 32 + ft * 16 + qm) * 128 + ko);
      Bg[ft][kk] = *(const bf16x8*)(Wc + (size_t)(nbase + 128 + wv * 32 + ft * 16 + qm) * 128 + ko);
    }

  int4 mi4[4];
#pragma unroll
  for (int m = 0; m < 4; m++) mi4[m] = *(const int4*)(mask + r0 + m * 16 + quad * 4);

  float bF_[2], bG_[2];
#pragma unroll
  for (int ft = 0; ft < 2; ft++) {
    int c = wv * 32 + ft * 16 + qm;
    bF_[ft] = bc[nbase + c];
    bG_[ft] = bc[nbase + 128 + c];
  }

#pragma unroll
  for (int m = 0; m < 4; m++) { // 4 row-steps of 16 rows — pure compute now
    f32x4 accf[2], accg[2];
#pragma unroll
    for (int ft = 0; ft < 2; ft++) {
      accf[ft] = (f32x4){0.f, 0.f, 0.f, 0.f};
      accg[ft] = (f32x4){0.f, 0.f, 0.f, 0.f};
    }
#pragma unroll
    for (int kk = 0; kk < 4; kk++) {
#pragma unroll
      for (int ft = 0; ft < 2; ft++) {
        accf[ft] = __builtin_amdgcn_mfma_f32_16x16x32_bf16(Areg[m][kk], Bf[ft][kk], accf[ft], 0, 0, 0);
        accg[ft] = __builtin_amdgcn_mfma_f32_16x16x32_bf16(Areg[m][kk], Bg[ft][kk], accg[ft], 0, 0, 0);
      }
    }
    int4 mi = mi4[m];
    float mk[4] = {mi.x ? 1.f : 0.f, mi.y ? 1.f : 0.f, mi.z ? 1.f : 0.f, mi.w ? 1.f : 0.f};
#pragma unroll
    for (int ft = 0; ft < 2; ft++) {
      int c = wv * 32 + ft * 16 + qm; // local col 0..127
      float v0 = (accf[ft][0] + bF_[ft]) * sigmoidf(accg[ft][0] + bG_[ft]) * mk[0];
      float v1 = (accf[ft][1] + bF_[ft]) * sigmoidf(accg[ft][1] + bG_[ft]) * mk[1];
      float v2 = (accf[ft][2] + bF_[ft]) * sigmoidf(accg[ft][2] + bG_[ft]) * mk[2];
      float v3 = (accf[ft][3] + bF_[ft]) * sigmoidf(accg[ft][3] + bG_[ft]) * mk[3];
      unsigned int u0 = (unsigned int)f2bf(v0) | ((unsigned int)f2bf(v1) << 16);
      unsigned int u1 = (unsigned int)f2bf(v2) | ((unsigned int)f2bf(v3) << 16);
      *(uint2*)(Cs + c * 36 + m * 8 + quad * 2) = (uint2){u0, u1};
    }
  }
  __syncthreads();
  { // wave writes its own 32 planes; 8 lanes/plane -> 128B contiguous lines
    unsigned short* dst = (nb == 0) ? toT : fromT;
    int pl = lane >> 3, lo = lane & 7;
#pragma unroll
    for (int i = 0; i < 4; i++) {
      int p = wv * 32 + i * 8 + pl;
      uint4 v = *(const uint4*)(Cs + p * 36 + lo * 4);
      *(uint4*)(dst + (size_t)p * RTOT + r0 + lo * 8) = v;
    }
  }
}

// ---------------------------------------------------------------------------
// K1b (FALLBACK ONLY, used when workspace too small to de-alias triT):
// out_gate = sigmoid(x @ W_go^T + b_go) * mask, fp32, into d_out.
// ---------------------------------------------------------------------------
__global__ __launch_bounds__(256) void go_gemm_kernel(
    const unsigned short* __restrict__ xb, const unsigned short* __restrict__ Wc,
    const float* __restrict__ bc, const int* __restrict__ mask,
    float* __restrict__ gate_out) {
  int wv = threadIdx.x >> 6, lane = threadIdx.x & 63;
  int qm = lane & 15, quad = lane >> 4;
  int rw = blockIdx.x * 64 + wv * 16;

  f32x4 acc[8];
#pragma unroll
  for (int t = 0; t < 8; t++) acc[t] = (f32x4){0.f, 0.f, 0.f, 0.f};

#pragma unroll
  for (int kk = 0; kk < 4; kk++) {
    int ko = kk * 32 + quad * 8;
    bf16x8 a = *(const bf16x8*)(xb + (size_t)(rw + qm) * 128 + ko);
#pragma unroll
    for (int t = 0; t < 8; t++) {
      bf16x8 bf = *(const bf16x8*)(Wc + (size_t)(512 + t * 16 + qm) * 128 + ko);
      acc[t] = __builtin_amdgcn_mfma_f32_16x16x32_bf16(a, bf, acc[t], 0, 0, 0);
    }
  }

  int rbase = rw + quad * 4;
  int4 mi = *(const int4*)(mask + rbase);
  float mk[4] = {mi.x ? 1.f : 0.f, mi.y ? 1.f : 0.f, mi.z ? 1.f : 0.f, mi.w ? 1.f : 0.f};
#pragma unroll
  for (int t = 0; t < 8; t++) {
    int c = t * 16 + qm;
    float bG = bc[512 + c];
#pragma unroll
    for (int reg = 0; reg < 4; reg++) {
      float g = sigmoidf(acc[t][reg] + bG) * mk[reg];
      gate_out[(size_t)(rbase + reg) * 128 + c] = g;
    }
  }
}

// ---------------------------------------------------------------------------
// K2: tri[d] = To_d (512x512) @ From_d^T, 128 batched NT GEMMs.
// 128x128 tile/block, BK=64, global_load_lds(16B) staging, 4 waves x (4x4)
// MFMA accs.  XCD d-clustered swizzle: linear wgid round-robins XCDs (n%8),
// so map XCD k -> d in [16k,16k+16): the 16 blocks sharing a d-plane's A/B
// panels co-reside on ONE XCD's L2 instead of interleaving all 128 d's.
// ---------------------------------------------------------------------------
__global__ __launch_bounds__(256) void tri_gemm_kernel(
    const unsigned short* __restrict__ toT, const unsigned short* __restrict__ fromT,
    unsigned short* __restrict__ triT) {
  __shared__ unsigned short smem[128 * 136]; // K-loop: As=[0,8192) Bs=[8192,16384); epilogue: C 128x136
  unsigned short* As = smem;
  unsigned short* Bs = smem + 128 * 64;

  // bijective remap of (x,y,z) -> (i0,j0,d), d-clustered per XCD
  int n = (int)(blockIdx.x + (blockIdx.y << 2) + (blockIdx.z << 4)); // 0..2047
  int xcd = n & 7, s = n >> 3;                                        // s: 0..255
  int d = xcd * 16 + (s >> 4);
  int xy = s & 15;
  int i0 = (xy & 3) * 128, j0 = (xy >> 2) * 128;

  int tid = threadIdx.x, w = tid >> 6, lane = tid & 63;
  int qm = lane & 15, quad = lane >> 4;
  int wm = w >> 1, wn = w & 1;
  const unsigned short* A = toT + (size_t)d * RTOT;
  const unsigned short* B = fromT + (size_t)d * RTOT;
  int lr = lane >> 3, lk = (lane & 7) * 8;

  f32x4 acc[4][4];
#pragma unroll
  for (int m = 0; m < 4; m++)
#pragma unroll
    for (int n2 = 0; n2 < 4; n2++) acc[m][n2] = (f32x4){0.f, 0.f, 0.f, 0.f};

  for (int kb = 0; kb < 512; kb += 64) {
    __syncthreads(); // prev compute done reading LDS
#pragma unroll
    for (int q = 0; q < 4; q++) {
      int blk = w * 4 + q; // 16 row-blocks of 8 rows each
      async16(A + (size_t)(i0 + blk * 8 + lr) * 512 + kb + lk, As + blk * 512);
      async16(B + (size_t)(j0 + blk * 8 + lr) * 512 + kb + lk, Bs + blk * 512);
    }
    __syncthreads(); // loads drained (compiler emits vmcnt(0) before barrier)
#pragma unroll
    for (int kk = 0; kk < 2; kk++) {
      bf16x8 af[4], bfr[4];
#pragma unroll
      for (int m = 0; m < 4; m++)
        af[m] = *(const bf16x8*)(As + (wm * 64 + m * 16 + qm) * 64 + kk * 32 + quad * 8);
#pragma unroll
      for (int n2 = 0; n2 < 4; n2++)
        bfr[n2] = *(const bf16x8*)(Bs + (wn * 64 + n2 * 16 + qm) * 64 + kk * 32 + quad * 8);
#pragma unroll
      for (int m = 0; m < 4; m++)
#pragma unroll
        for (int n2 = 0; n2 < 4; n2++)
          acc[m][n2] = __builtin_amdgcn_mfma_f32_16x16x32_bf16(af[m], bfr[n2], acc[m][n2], 0, 0, 0);
    }
  }

  __syncthreads(); // done with As/Bs; reuse smem as C 128x136 (pad keeps 16B align, kills conflicts)
#pragma unroll
  for (int m = 0; m < 4; m++) {
    int rb = wm * 64 + m * 16 + quad * 4;
#pragma unroll
    for (int n2 = 0; n2 < 4; n2++) {
      int col = wn * 64 + n2 * 16 + qm;
#pragma unroll
      for (int reg = 0; reg < 4; reg++)
        smem[(rb + reg) * 136 + col] = f2bf(acc[m][n2][reg]);
    }
  }
  __syncthreads();
  { // each (row, half) copies its FULL 64-short half: 8 x uint4
    int row = tid >> 1, half = tid & 1;
    const uint4* src = (const uint4*)(smem + row * 136 + half * 64);
    uint4 v[8];
#pragma unroll
    for (int u = 0; u < 8; u++) v[u] = src[u];
    uint4* dst = (uint4*)(triT + (size_t)d * RTOT + (size_t)(i0 + row) * 512 + j0 + half * 64);
#pragma unroll
    for (int u = 0; u < 8; u++) dst[u] = v[u];
  }
}

// ---------------------------------------------------------------------------
// K3: LN2 over d=128 of tri (channel-major input), @ W_out^T + b_out, * gate.
// 128-row blocks; channel-major read chunks 256B; all global reads in one
// prologue burst; gate A2 software-pipelined across m.
// ---------------------------------------------------------------------------
__global__ __launch_bounds__(256) void out_kernel(
    const unsigned short* __restrict__ triT, const unsigned short* __restrict__ Woutb,
    const float* __restrict__ ln2w, const float* __restrict__ ln2b,
    const float* __restrict__ b_out, float* __restrict__ out,
    const unsigned short* __restrict__ xb, const unsigned short* __restrict__ Wc,
    const float* __restrict__ bc, const int* __restrict__ mask, int fuse) {
  __shared__ unsigned short nt[128][136];
  __shared__ float mu_s[128], rs_s[128];
  int r0 = blockIdx.x * 128;
  int tid = threadIdx.x;
  int wv = tid >> 6, lane = tid & 63;
  int qm = lane & 15, quad = lane >> 4;

  // ---- prologue: issue every global read up front (max MLP) ----
  int dch = tid >> 1, half = tid & 1; // dch: 0..127 channel, half: 64 positions each
  const uint4* src = (const uint4*)(triT + (size_t)dch * RTOT + r0 + half * 64);
  uint4 sv[8];
#pragma unroll
  for (int u = 0; u < 8; u++) sv[u] = src[u];

  // B fragments for this wave's 32 output cols.
  bf16x8 Bo[2][4], Bg[2][4];
#pragma unroll
  for (int ft = 0; ft < 2; ft++)
#pragma unroll
    for (int kk = 0; kk < 4; kk++) {
      int c = wv * 32 + ft * 16 + qm;
      int ko = kk * 32 + quad * 8;
      Bo[ft][kk] = *(const bf16x8*)(Woutb + (size_t)c * 128 + ko);
      if (fuse) Bg[ft][kk] = *(const bf16x8*)(Wc + (size_t)(512 + c) * 128 + ko);
    }

  // masks for all 8 m-steps; bias scalars.
  int4 mi4[8];
  float bo_[2], bG_[2];
#pragma unroll
  for (int ft = 0; ft < 2; ft++) {
    int c = wv * 32 + ft * 16 + qm;
    bo_[ft] = b_out[c];
    bG_[ft] = fuse ? bc[512 + c] : 0.f;
  }
  if (fuse) {
#pragma unroll
    for (int m = 0; m < 8; m++) mi4[m] = *(const int4*)(mask + r0 + m * 16 + quad * 4);
  }

  // gate A2: prefetch m=0 (double-buffered across the m-loop).
  const unsigned short* xA = xb + (size_t)(r0 + qm) * 128 + quad * 8;
  bf16x8 a2cur[4], a2nxt[4];
  if (fuse) {
#pragma unroll
    for (int kk = 0; kk < 4; kk++) a2cur[kk] = *(const bf16x8*)(xA + kk * 32);
  }

  { // LDS staging writes (vmcnt waits only on the sv loads)
    const unsigned short* pv = (const unsigned short*)sv;
#pragma unroll
    for (int u = 0; u < 64; u++) nt[half * 64 + u][dch] = pv[u];
  }
  __syncthreads();

  { // LN2 stats: 2 lanes per position (each sums 64 channels)
    int p = tid >> 1, part = tid & 1;
    float s = 0.f, sq = 0.f;
#pragma unroll
    for (int u = 0; u < 8; u++) {
      bf16x8 v = *(const bf16x8*)(&nt[p][part * 64 + u * 8]);
#pragma unroll
      for (int e = 0; e < 8; e++) {
        float f = bf2f((unsigned short)v[e]);
        s += f; sq += f * f;
      }
    }
    s += __shfl_xor(s, 1); sq += __shfl_xor(sq, 1);
    float mu = s * (1.f / 128.f);
    float var = sq * (1.f / 128.f) - mu * mu;
    if (part == 0) { mu_s[p] = mu; rs_s[p] = rsqrtf(var + 1e-5f); }
  }
  __syncthreads();

#pragma unroll
  for (int m = 0; m < 8; m++) { // 8 row-steps of 16 rows
    // prefetch next m's gate A2 first: latency hides under afr VALU + MFMA
    if (fuse && m < 7) {
#pragma unroll
      for (int kk = 0; kk < 4; kk++)
        a2nxt[kk] = *(const bf16x8*)(xA + (m + 1) * 2048 + kk * 32);
    }

    int rl = m * 16 + qm;
    float mu = mu_s[rl], rs = rs_s[rl];

    // Build normalized A-fragments in registers.
    bf16x8 afr[4];
#pragma unroll
    for (int kk = 0; kk < 4; kk++) {
      int ko = kk * 32 + quad * 8;
      bf16x8 raw = *(const bf16x8*)(&nt[rl][ko]);
#pragma unroll
      for (int e = 0; e < 8; e++) {
        float wf = ln2w[ko + e], bv = ln2b[ko + e];
        afr[kk][e] = (short)f2bf((bf2f((unsigned short)raw[e]) - mu) * rs * wf + bv);
      }
    }

    f32x4 accO[2], accG[2];
#pragma unroll
    for (int ft = 0; ft < 2; ft++) {
      accO[ft] = (f32x4){0.f, 0.f, 0.f, 0.f};
      accG[ft] = (f32x4){0.f, 0.f, 0.f, 0.f};
    }
#pragma unroll
    for (int kk = 0; kk < 4; kk++) {
#pragma unroll
      for (int ft = 0; ft < 2; ft++)
        accO[ft] = __builtin_amdgcn_mfma_f32_16x16x32_bf16(afr[kk], Bo[ft][kk], accO[ft], 0, 0, 0);
      if (fuse) {
#pragma unroll
        for (int ft = 0; ft < 2; ft++)
          accG[ft] = __builtin_amdgcn_mfma_f32_16x16x32_bf16(a2cur[kk], Bg[ft][kk], accG[ft], 0, 0, 0);
      }
    }

    int rbase = r0 + m * 16 + quad * 4;
    if (fuse) {
      int4 mi = mi4[m];
      float mk[4] = {mi.x ? 1.f : 0.f, mi.y ? 1.f : 0.f, mi.z ? 1.f : 0.f, mi.w ? 1.f : 0.f};
#pragma unroll
      for (int ft = 0; ft < 2; ft++) {
        int c = wv * 32 + ft * 16 + qm;
#pragma unroll
        for (int reg = 0; reg < 4; reg++) {
          float g = sigmoidf(accG[ft][reg] + bG_[ft]) * mk[reg];
          out[(size_t)(rbase + reg) * 128 + c] = (accO[ft][reg] + bo_[ft]) * g;
        }
      }
      // rotate double-buffer (register moves, static after unroll)
#pragma unroll
      for (int kk = 0; kk < 4; kk++) a2cur[kk] = a2nxt[kk];
    } else {
#pragma unroll
      for (int ft = 0; ft < 2; ft++) {
        int c = wv * 32 + ft * 16 + qm;
#pragma unroll
        for (int reg = 0; reg < 4; reg++) {
          size_t off = (size_t)(rbase + reg) * 128 + c;
          out[off] = (accO[ft][reg] + bo_[ft]) * out[off]; // out[] holds gate
        }
      }
    }
  }
}

// ---------------------------------------------------------------------------
extern "C" void kernel_launch(void* const* d_in, const int* in_sizes, int n_in,
                              void* d_out, int out_size, void* d_ws, size_t ws_size,
                              hipStream_t stream) {
  const float* edges = (const float*)d_in[0];
  const int* mask = (const int*)d_in[1];
  const float* ln1w = (const float*)d_in[2];
  const float* ln1b = (const float*)d_in[3];
  const float* W_fg = (const float*)d_in[4];
  const float* b_fg = (const float*)d_in[5];
  const float* W_go = (const float*)d_in[6];
  const float* b_go = (const float*)d_in[7];
  const float* ln2w = (const float*)d_in[8];
  const float* ln2b = (const float*)d_in[9];
  const float* W_out = (const float*)d_in[10];
  const float* b_out = (const float*)d_in[11];

  char* ws = (char*)d_ws;
  const size_t SZ = (size_t)RTOT * DCH * 2; // 64 MiB per bf16 buffer
  const size_t WSMALL = 0x40000;            // 256 KiB: Wc(160K)+bc(2.5K)+Woutb(32K), padded
  unsigned short* xb = (unsigned short*)ws;
  unsigned short* toT = (unsigned short*)(ws + SZ);
  unsigned short* fromT = (unsigned short*)(ws + 2 * SZ);
  unsigned short* Wc = (unsigned short*)(ws + 3 * SZ);
  float* bc = (float*)(ws + 3 * SZ + 640 * 128 * 2);
  unsigned short* Woutb = (unsigned short*)(ws + 3 * SZ + 640 * 128 * 2 + 640 * 4);
  float* gate = (float*)d_out;

  // If workspace allows, give triT its own buffer so xb survives -> fuse the
  // gate GEMM into out_kernel (kills 256 MiB of fp32 gate traffic + 1 launch).
  bool fits = ws_size >= 4 * SZ + WSMALL;
  unsigned short* triT = fits ? (unsigned short*)(ws + 3 * SZ + WSMALL) : xb;

  prep_kernel<<<384, 256, 0, stream>>>(W_fg, b_fg, W_go, b_go, W_out, Wc, bc, Woutb);
  ln1_kernel<<<RTOT / 4, 256, 0, stream>>>(edges, ln1w, ln1b, xb);
  fg_gemm_kernel<<<dim3(RTOT / 64, 2), 256, 0, stream>>>(xb, Wc, bc, mask, toT, fromT);
  if (!fits) go_gemm_kernel<<<RTOT / 64, 256, 0, stream>>>(xb, Wc, bc, mask, gate);
  tri_gemm_kernel<<<dim3(4, 4, 128), 256, 0, stream>>>(toT, fromT, triT);
  out_kernel<<<RTOT / 128, 256, 0, stream>>>(triT, Woutb, ln2w, ln2b, b_out,
                                             (float*)d_out, xb, Wc, bc, mask, fits ? 1 : 0);
}